// Round 1
// baseline (4108.291 us; speedup 1.0000x reference)
//
#include <hip/hip_runtime.h>

#define NGRID 65160          // 181*360 grid nodes
#define NMESH 40962
#define NTOT  (NGRID + NMESH) // 106122
#define CIN   69
#define HID   256
#define HH    181
#define WWID  360

__device__ __forceinline__ float gelu_exact(float v) {
    return 0.5f * v * (1.0f + erff(v * 0.7071067811865476f));
}

// ---------------- feature build: h0 (NTOT x 69 row-major) ----------------
__global__ void build_feats(const float* __restrict__ x, const int* __restrict__ Lat,
                            const int* __restrict__ Lon, float* __restrict__ h0) {
    long long t = (long long)blockIdx.x * blockDim.x + threadIdx.x;
    if (t >= (long long)NTOT * CIN) return;
    int i = (int)(t / CIN);
    int c = (int)(t - (long long)i * CIN);
    const float* xc = x + (size_t)c * (HH * WWID);
    float val;
    if (i < NGRID) {
        val = xc[i];
    } else {
        int j = i - NGRID;
        int la = Lat[j] - 1;   // 0..720
        int lo = Lon[j] - 1;   // 0..1439
        if (la == 720) {
            val = xc[180 * WWID + 0];   // pole value x[c, -1, 0]
        } else {
            float sh = fmaxf((la + 0.5f) * 0.25f - 0.5f, 0.0f);
            int i0 = (int)floorf(sh); if (i0 > HH - 2) i0 = HH - 2; // 0..179
            int i1 = i0 + 1; if (i1 > HH - 2) i1 = HH - 2;
            float wh = sh - (float)i0;
            float sw = fmaxf((lo + 0.5f) * 0.25f - 0.5f, 0.0f);
            int j0 = (int)floorf(sw); if (j0 > WWID - 1) j0 = WWID - 1;
            int j1 = j0 + 1; if (j1 > WWID - 1) j1 = WWID - 1;
            float ww = sw - (float)j0;
            float a = xc[i0 * WWID + j0] * (1.f - wh) + xc[i1 * WWID + j0] * wh;
            float b = xc[i0 * WWID + j1] * (1.f - wh) + xc[i1 * WWID + j1] * wh;
            val = a * (1.f - ww) + b * ww;
        }
    }
    h0[(size_t)i * CIN + c] = val;
}

// ---------------- degree / norm ----------------
__global__ void deg_init(float* __restrict__ deg) {
    int i = blockIdx.x * 256 + threadIdx.x;
    if (i < NTOT) deg[i] = 1.0f;   // self loop
}
__global__ void deg_scatter(const int* __restrict__ ei, float* __restrict__ deg, int E) {
    int e = blockIdx.x * 256 + threadIdx.x;
    if (e < E) atomicAdd(&deg[ei[E + e]], 1.0f);
}
__global__ void dinv_k(const float* __restrict__ deg, float* __restrict__ dinv) {
    int i = blockIdx.x * 256 + threadIdx.x;
    if (i < NTOT) {
        float d = deg[i];
        dinv[i] = d > 0.f ? 1.0f / sqrtf(d) : 0.0f;
    }
}

// ---------------- fp32 GEMM: out(N x 256) = A(N x K) @ W(K x 256) [+bias][gelu] --------
template<int BIAS, int GELU>
__global__ __launch_bounds__(256) void gemm_k(const float* __restrict__ A,
                                              const float* __restrict__ W,
                                              const float* __restrict__ bias,
                                              float* __restrict__ out,
                                              int Nrows, int K) {
    __shared__ float As[8][132];  // [k][row], padded
    __shared__ float Bs[8][128];  // [k][col]
    const int row0 = blockIdx.y * 128;
    const int col0 = blockIdx.x * 128;
    const int t = threadIdx.x;
    const int tr = t / 16, tc = t % 16;
    float acc[8][8] = {};
    for (int kk = 0; kk < K; kk += 8) {
#pragma unroll
        for (int i = 0; i < 4; ++i) {
            int r = (t >> 3) + i * 32;
            int k = t & 7;
            int gr = row0 + r, gk = kk + k;
            float v = 0.f;
            if (gr < Nrows && gk < K) v = A[(size_t)gr * K + gk];
            As[k][r] = v;
        }
#pragma unroll
        for (int i = 0; i < 4; ++i) {
            int c = t & 127;
            int k = (t >> 7) + i * 2;
            int gk = kk + k;
            float v = 0.f;
            if (gk < K) v = W[(size_t)gk * HID + col0 + c];
            Bs[k][c] = v;
        }
        __syncthreads();
#pragma unroll
        for (int k = 0; k < 8; ++k) {
            float a[8], b[8];
            *(float4*)&a[0] = *(const float4*)&As[k][tr * 8];
            *(float4*)&a[4] = *(const float4*)&As[k][tr * 8 + 4];
            *(float4*)&b[0] = *(const float4*)&Bs[k][tc * 8];
            *(float4*)&b[4] = *(const float4*)&Bs[k][tc * 8 + 4];
#pragma unroll
            for (int i = 0; i < 8; ++i)
#pragma unroll
                for (int j = 0; j < 8; ++j)
                    acc[i][j] = fmaf(a[i], b[j], acc[i][j]);
        }
        __syncthreads();
    }
#pragma unroll
    for (int i = 0; i < 8; ++i) {
        int gr = row0 + tr * 8 + i;
        if (gr < Nrows) {
#pragma unroll
            for (int j = 0; j < 8; ++j) {
                int gc = col0 + tc * 8 + j;
                float v = acc[i][j];
                if (BIAS) v += bias[gc];
                if (GELU) v = gelu_exact(v);
                out[(size_t)gr * HID + gc] = v;
            }
        }
    }
}

// ---------------- aggregation ----------------
// out[i,:] = bias + dinv[i]^2 * tmp[i,:]   (self loop + bias, non-atomic)
__global__ void agg_init(const float* __restrict__ tmp, const float* __restrict__ dinv,
                         const float* __restrict__ bias, float* __restrict__ out) {
    long long t = (long long)blockIdx.x * 256 + threadIdx.x;  // over NTOT*64 float4s
    if (t >= (long long)NTOT * 64) return;
    int i = (int)(t >> 6);
    int f4 = (int)(t & 63);
    float w = dinv[i]; w = w * w;
    float4 v = ((const float4*)tmp)[t];
    float4 bb = ((const float4*)bias)[f4];
    float4 o;
    o.x = bb.x + w * v.x;
    o.y = bb.y + w * v.y;
    o.z = bb.z + w * v.z;
    o.w = bb.w + w * v.w;
    ((float4*)out)[t] = o;
}

// one wave per edge; lane handles 4 features
__global__ void edge_scatter(const int* __restrict__ ei, const float* __restrict__ dinv,
                             const float* __restrict__ tmp, float* __restrict__ out, int E) {
    int g = blockIdx.x * 256 + threadIdx.x;
    int e = g >> 6;
    if (e >= E) return;
    int lane = g & 63;
    int s = ei[e], d = ei[E + e];
    float w = dinv[s] * dinv[d];
    float4 v = ((const float4*)(tmp + (size_t)s * HID))[lane];
    float* o = out + (size_t)d * HID + lane * 4;
    atomicAdd(o + 0, v.x * w);
    atomicAdd(o + 1, v.y * w);
    atomicAdd(o + 2, v.z * w);
    atomicAdd(o + 3, v.w * w);
}

__global__ void gelu_k(float* __restrict__ a) {
    long long t = (long long)blockIdx.x * 256 + threadIdx.x;
    if (t >= (long long)NTOT * 64) return;
    float4 v = ((float4*)a)[t];
    v.x = gelu_exact(v.x); v.y = gelu_exact(v.y);
    v.z = gelu_exact(v.z); v.w = gelu_exact(v.w);
    ((float4*)a)[t] = v;
}

// ---------------- final transpose: (NMESH x 256) -> (256 x NMESH) ----------------
__global__ void transpose_k(const float* __restrict__ in, float* __restrict__ out) {
    __shared__ float tile[32][33];
    int jb = blockIdx.x * 32;   // node block
    int fb = blockIdx.y * 32;   // feature block
    int tx = threadIdx.x & 31, ty = threadIdx.x >> 5;  // 32x8
#pragma unroll
    for (int i = 0; i < 32; i += 8) {
        int j = jb + ty + i;
        float v = 0.f;
        if (j < NMESH) v = in[(size_t)j * HID + fb + tx];
        tile[ty + i][tx] = v;
    }
    __syncthreads();
#pragma unroll
    for (int i = 0; i < 32; i += 8) {
        int f = fb + ty + i;
        int j = jb + tx;
        if (j < NMESH) out[(size_t)f * NMESH + j] = tile[tx][ty + i];
    }
}

extern "C" void kernel_launch(void* const* d_in, const int* in_sizes, int n_in,
                              void* d_out, int out_size, void* d_ws, size_t ws_size,
                              hipStream_t stream) {
    const float* x   = (const float*)d_in[0];
    const int*   ei  = (const int*)d_in[1];
    const int*   Lat = (const int*)d_in[2];
    const int*   Lon = (const int*)d_in[3];
    const float* W1  = (const float*)d_in[4];
    const float* b1  = (const float*)d_in[5];
    const float* W2  = (const float*)d_in[6];
    const float* b2  = (const float*)d_in[7];
    const float* Wl  = (const float*)d_in[8];
    const float* bl  = (const float*)d_in[9];
    const float* Wl1 = (const float*)d_in[10];
    const float* bl1 = (const float*)d_in[11];
    float* out = (float*)d_out;
    const int E = in_sizes[1] / 2;

    float* A    = (float*)d_ws;                 // NTOT*256
    float* Bb   = A    + (size_t)NTOT * HID;    // NTOT*256
    float* h0   = Bb   + (size_t)NTOT * HID;    // NTOT*69
    float* deg  = h0   + (size_t)NTOT * CIN;    // NTOT
    float* dinv = deg  + NTOT;                  // NTOT

    // 1. features
    {
        long long tot = (long long)NTOT * CIN;
        build_feats<<<(int)((tot + 255) / 256), 256, 0, stream>>>(x, Lat, Lon, h0);
    }
    // 2. degree / norm
    deg_init<<<(NTOT + 255) / 256, 256, 0, stream>>>(deg);
    deg_scatter<<<(E + 255) / 256, 256, 0, stream>>>(ei, deg, E);
    dinv_k<<<(NTOT + 255) / 256, 256, 0, stream>>>(deg, dinv);

    const int nv = (int)(((long long)NTOT * 64 + 255) / 256);
    dim3 gFull(2, (NTOT + 127) / 128);
    dim3 gMesh(2, (NMESH + 127) / 128);

    // 3. GCN layer 1
    gemm_k<0, 0><<<gFull, 256, 0, stream>>>(h0, W1, nullptr, Bb, NTOT, CIN);
    agg_init<<<nv, 256, 0, stream>>>(Bb, dinv, b1, A);
    edge_scatter<<<(int)(((long long)E * 64 + 255) / 256), 256, 0, stream>>>(ei, dinv, Bb, A, E);
    gelu_k<<<nv, 256, 0, stream>>>(A);

    // 4. GCN layer 2
    gemm_k<0, 0><<<gFull, 256, 0, stream>>>(A, W2, nullptr, Bb, NTOT, HID);
    agg_init<<<nv, 256, 0, stream>>>(Bb, dinv, b2, A);
    edge_scatter<<<(int)(((long long)E * 64 + 255) / 256), 256, 0, stream>>>(ei, dinv, Bb, A, E);

    // 5. mesh head: t1 = hm @ Wl + bl ; t2 = gelu(t1 @ Wl1 + bl1)
    gemm_k<1, 0><<<gMesh, 256, 0, stream>>>(A + (size_t)NGRID * HID, Wl, bl, Bb, NMESH, HID);
    gemm_k<1, 1><<<gMesh, 256, 0, stream>>>(Bb, Wl1, bl1, A, NMESH, HID);

    // 6. transpose to (256, NMESH)
    dim3 gT((NMESH + 31) / 32, HID / 32);
    transpose_k<<<gT, 256, 0, stream>>>(A, out);
}

// Round 2
// 860.969 us; speedup vs baseline: 4.7717x; 4.7717x over previous
//
#include <hip/hip_runtime.h>

#define NGRID 65160          // 181*360 grid nodes
#define NMESH 40962
#define NTOT  (NGRID + NMESH) // 106122
#define CIN   69
#define HID   256
#define HH    181
#define WWID  360
#define SCAN_BS 1024
#define NBLK_SCAN ((NTOT + SCAN_BS - 1) / SCAN_BS)   // 104

__device__ __forceinline__ float gelu_exact(float v) {
    return 0.5f * v * (1.0f + erff(v * 0.7071067811865476f));
}

// ---------------- feature build: h0 (NTOT x 69 row-major) ----------------
__global__ void build_feats(const float* __restrict__ x, const int* __restrict__ Lat,
                            const int* __restrict__ Lon, float* __restrict__ h0) {
    long long t = (long long)blockIdx.x * blockDim.x + threadIdx.x;
    if (t >= (long long)NTOT * CIN) return;
    int i = (int)(t / CIN);
    int c = (int)(t - (long long)i * CIN);
    const float* xc = x + (size_t)c * (HH * WWID);
    float val;
    if (i < NGRID) {
        val = xc[i];
    } else {
        int j = i - NGRID;
        int la = Lat[j] - 1;   // 0..720
        int lo = Lon[j] - 1;   // 0..1439
        if (la == 720) {
            val = xc[180 * WWID + 0];   // pole value x[c, -1, 0]
        } else {
            float sh = fmaxf((la + 0.5f) * 0.25f - 0.5f, 0.0f);
            int i0 = (int)floorf(sh); if (i0 > HH - 2) i0 = HH - 2;
            int i1 = i0 + 1; if (i1 > HH - 2) i1 = HH - 2;
            float wh = sh - (float)i0;
            float sw = fmaxf((lo + 0.5f) * 0.25f - 0.5f, 0.0f);
            int j0 = (int)floorf(sw); if (j0 > WWID - 1) j0 = WWID - 1;
            int j1 = j0 + 1; if (j1 > WWID - 1) j1 = WWID - 1;
            float ww = sw - (float)j0;
            float a = xc[i0 * WWID + j0] * (1.f - wh) + xc[i1 * WWID + j0] * wh;
            float b = xc[i0 * WWID + j1] * (1.f - wh) + xc[i1 * WWID + j1] * wh;
            val = a * (1.f - ww) + b * ww;
        }
    }
    h0[(size_t)i * CIN + c] = val;
}

// ---------------- degree / norm ----------------
__global__ void deg_init(float* __restrict__ deg, int* __restrict__ cnt) {
    int i = blockIdx.x * 256 + threadIdx.x;
    if (i < NTOT) { deg[i] = 1.0f; cnt[i] = 0; }
}
__global__ void deg_scatter(const int* __restrict__ ei, float* __restrict__ deg, int E) {
    int e = blockIdx.x * 256 + threadIdx.x;
    if (e < E) atomicAdd(&deg[ei[E + e]], 1.0f);
}
__global__ void dinv_k(const float* __restrict__ deg, float* __restrict__ dinv) {
    int i = blockIdx.x * 256 + threadIdx.x;
    if (i < NTOT) {
        float d = deg[i];
        dinv[i] = d > 0.f ? 1.0f / sqrtf(d) : 0.0f;
    }
}

// ---------------- exclusive scan of in-degree -> CSR offsets ----------------
__global__ __launch_bounds__(SCAN_BS) void scan1(const float* __restrict__ deg,
                                                 int* __restrict__ off, int* __restrict__ bsum) {
    __shared__ int s[SCAN_BS];
    int t = threadIdx.x;
    int i = blockIdx.x * SCAN_BS + t;
    int v = (i < NTOT) ? ((int)deg[i] - 1) : 0;
    s[t] = v; __syncthreads();
    for (int d = 1; d < SCAN_BS; d <<= 1) {
        int x = (t >= d) ? s[t - d] : 0;
        __syncthreads();
        s[t] += x;
        __syncthreads();
    }
    if (i < NTOT) off[i] = s[t] - v;          // exclusive
    if (t == SCAN_BS - 1) bsum[blockIdx.x] = s[t];
}
__global__ void scan2(int* __restrict__ bsum) {
    __shared__ int s[128];
    int t = threadIdx.x;
    int v = (t < NBLK_SCAN) ? bsum[t] : 0;
    s[t] = v; __syncthreads();
    for (int d = 1; d < 128; d <<= 1) {
        int x = (t >= d) ? s[t - d] : 0;
        __syncthreads();
        s[t] += x;
        __syncthreads();
    }
    if (t < NBLK_SCAN) bsum[t] = s[t] - v;    // exclusive block offsets
}
__global__ __launch_bounds__(SCAN_BS) void scan3(int* __restrict__ off, const int* __restrict__ bsum) {
    int i = blockIdx.x * SCAN_BS + threadIdx.x;
    if (i < NTOT) off[i] += bsum[blockIdx.x];
}

// ---------------- CSR fill ----------------
__global__ void csr_fill(const int* __restrict__ ei, const float* __restrict__ dinv,
                         const int* __restrict__ off, int* __restrict__ cnt,
                         int* __restrict__ esrc, float* __restrict__ ewt, int E) {
    int e = blockIdx.x * 256 + threadIdx.x;
    if (e >= E) return;
    int s = ei[e], d = ei[E + e];
    int pos = off[d] + atomicAdd(&cnt[d], 1);
    esrc[pos] = s;
    ewt[pos] = dinv[s] * dinv[d];
}

// ---------------- fp32 GEMM: out(N x 256) = A(N x K) @ W(K x 256) [+bias][gelu] --------
template<int BIAS, int GELU>
__global__ __launch_bounds__(256) void gemm_k(const float* __restrict__ A,
                                              const float* __restrict__ W,
                                              const float* __restrict__ bias,
                                              float* __restrict__ out,
                                              int Nrows, int K) {
    __shared__ float As[8][132];
    __shared__ float Bs[8][128];
    const int row0 = blockIdx.y * 128;
    const int col0 = blockIdx.x * 128;
    const int t = threadIdx.x;
    const int tr = t / 16, tc = t % 16;
    float acc[8][8] = {};
    for (int kk = 0; kk < K; kk += 8) {
#pragma unroll
        for (int i = 0; i < 4; ++i) {
            int r = (t >> 3) + i * 32;
            int k = t & 7;
            int gr = row0 + r, gk = kk + k;
            float v = 0.f;
            if (gr < Nrows && gk < K) v = A[(size_t)gr * K + gk];
            As[k][r] = v;
        }
#pragma unroll
        for (int i = 0; i < 4; ++i) {
            int c = t & 127;
            int k = (t >> 7) + i * 2;
            int gk = kk + k;
            float v = 0.f;
            if (gk < K) v = W[(size_t)gk * HID + col0 + c];
            Bs[k][c] = v;
        }
        __syncthreads();
#pragma unroll
        for (int k = 0; k < 8; ++k) {
            float a[8], b[8];
            *(float4*)&a[0] = *(const float4*)&As[k][tr * 8];
            *(float4*)&a[4] = *(const float4*)&As[k][tr * 8 + 4];
            *(float4*)&b[0] = *(const float4*)&Bs[k][tc * 8];
            *(float4*)&b[4] = *(const float4*)&Bs[k][tc * 8 + 4];
#pragma unroll
            for (int i = 0; i < 8; ++i)
#pragma unroll
                for (int j = 0; j < 8; ++j)
                    acc[i][j] = fmaf(a[i], b[j], acc[i][j]);
        }
        __syncthreads();
    }
#pragma unroll
    for (int i = 0; i < 8; ++i) {
        int gr = row0 + tr * 8 + i;
        if (gr < Nrows) {
#pragma unroll
            for (int j = 0; j < 8; ++j) {
                int gc = col0 + tc * 8 + j;
                float v = acc[i][j];
                if (BIAS) v += bias[gc];
                if (GELU) v = gelu_exact(v);
                out[(size_t)gr * HID + gc] = v;
            }
        }
    }
}

// ---------------- gather aggregation: one wave per dst ----------------
// out[d,:] = [gelu]( bias + dinv[d]^2*tmp[d,:] + sum_e w_e * tmp[src_e,:] )
template<int GELU>
__global__ __launch_bounds__(256) void gather_agg(const float* __restrict__ tmp,
                                                  const float* __restrict__ deg,
                                                  const float* __restrict__ dinv,
                                                  const float* __restrict__ bias,
                                                  const int* __restrict__ off,
                                                  const int* __restrict__ esrc,
                                                  const float* __restrict__ ewt,
                                                  float* __restrict__ out,
                                                  int base, int ndst) {
    int wv = (blockIdx.x * 256 + threadIdx.x) >> 6;
    if (wv >= ndst) return;
    int d = base + wv;
    int lane = threadIdx.x & 63;
    float dv = dinv[d];
    float w2 = dv * dv;
    float4 acc = ((const float4*)bias)[lane];
    float4 v = ((const float4*)(tmp + (size_t)d * HID))[lane];
    acc.x = fmaf(w2, v.x, acc.x);
    acc.y = fmaf(w2, v.y, acc.y);
    acc.z = fmaf(w2, v.z, acc.z);
    acc.w = fmaf(w2, v.w, acc.w);
    int p0 = off[d];
    int p1 = p0 + ((int)deg[d] - 1);
    for (int p = p0; p < p1; ++p) {
        int s = esrc[p];
        float w = ewt[p];
        float4 u = ((const float4*)(tmp + (size_t)s * HID))[lane];
        acc.x = fmaf(w, u.x, acc.x);
        acc.y = fmaf(w, u.y, acc.y);
        acc.z = fmaf(w, u.z, acc.z);
        acc.w = fmaf(w, u.w, acc.w);
    }
    if (GELU) {
        acc.x = gelu_exact(acc.x);
        acc.y = gelu_exact(acc.y);
        acc.z = gelu_exact(acc.z);
        acc.w = gelu_exact(acc.w);
    }
    ((float4*)(out + (size_t)d * HID))[lane] = acc;
}

// ---------------- final transpose: (NMESH x 256) -> (256 x NMESH) ----------------
__global__ void transpose_k(const float* __restrict__ in, float* __restrict__ out) {
    __shared__ float tile[32][33];
    int jb = blockIdx.x * 32;
    int fb = blockIdx.y * 32;
    int tx = threadIdx.x & 31, ty = threadIdx.x >> 5;
#pragma unroll
    for (int i = 0; i < 32; i += 8) {
        int j = jb + ty + i;
        float v = 0.f;
        if (j < NMESH) v = in[(size_t)j * HID + fb + tx];
        tile[ty + i][tx] = v;
    }
    __syncthreads();
#pragma unroll
    for (int i = 0; i < 32; i += 8) {
        int f = fb + ty + i;
        int j = jb + tx;
        if (j < NMESH) out[(size_t)f * NMESH + j] = tile[tx][ty + i];
    }
}

extern "C" void kernel_launch(void* const* d_in, const int* in_sizes, int n_in,
                              void* d_out, int out_size, void* d_ws, size_t ws_size,
                              hipStream_t stream) {
    const float* x   = (const float*)d_in[0];
    const int*   ei  = (const int*)d_in[1];
    const int*   Lat = (const int*)d_in[2];
    const int*   Lon = (const int*)d_in[3];
    const float* W1  = (const float*)d_in[4];
    const float* b1  = (const float*)d_in[5];
    const float* W2  = (const float*)d_in[6];
    const float* b2  = (const float*)d_in[7];
    const float* Wl  = (const float*)d_in[8];
    const float* bl  = (const float*)d_in[9];
    const float* Wl1 = (const float*)d_in[10];
    const float* bl1 = (const float*)d_in[11];
    float* out = (float*)d_out;
    const int E = in_sizes[1] / 2;

    float* A    = (float*)d_ws;                  // NTOT*256
    float* Bb   = A    + (size_t)NTOT * HID;     // NTOT*256
    float* h0   = Bb   + (size_t)NTOT * HID;     // NTOT*69 (CSR esrc/ewt alias this after GEMM1)
    float* deg  = h0   + (size_t)NTOT * CIN;     // NTOT
    float* dinv = deg  + NTOT;                   // NTOT
    int*   off  = (int*)(dinv + NTOT);           // NTOT
    int*   cnt  = off + NTOT;                    // NTOT
    int*   bsum = cnt + NTOT;                    // NBLK_SCAN (pad 128)
    int*   esrc = (int*)h0;                      // E ints   (alias h0: used after GEMM1)
    float* ewt  = h0 + E;                        // E floats (alias h0)

    // 1. features
    {
        long long tot = (long long)NTOT * CIN;
        build_feats<<<(int)((tot + 255) / 256), 256, 0, stream>>>(x, Lat, Lon, h0);
    }
    // 2. degree / norm / CSR offsets
    deg_init<<<(NTOT + 255) / 256, 256, 0, stream>>>(deg, cnt);
    deg_scatter<<<(E + 255) / 256, 256, 0, stream>>>(ei, deg, E);
    dinv_k<<<(NTOT + 255) / 256, 256, 0, stream>>>(deg, dinv);
    scan1<<<NBLK_SCAN, SCAN_BS, 0, stream>>>(deg, off, bsum);
    scan2<<<1, 128, 0, stream>>>(bsum);
    scan3<<<NBLK_SCAN, SCAN_BS, 0, stream>>>(off, bsum);

    dim3 gFull(2, (NTOT + 127) / 128);
    dim3 gMesh(2, (NMESH + 127) / 128);

    // 3. GCN layer 1: GEMM, then build CSR (aliases h0), then gather(+bias+gelu)
    gemm_k<0, 0><<<gFull, 256, 0, stream>>>(h0, W1, nullptr, Bb, NTOT, CIN);
    csr_fill<<<(E + 255) / 256, 256, 0, stream>>>(ei, dinv, off, cnt, esrc, ewt, E);
    gather_agg<1><<<(int)(((long long)NTOT * 64 + 255) / 256), 256, 0, stream>>>(
        Bb, deg, dinv, b1, off, esrc, ewt, A, 0, NTOT);

    // 4. GCN layer 2: GEMM full, gather only mesh dsts (rest unused downstream)
    gemm_k<0, 0><<<gFull, 256, 0, stream>>>(A, W2, nullptr, Bb, NTOT, HID);
    gather_agg<0><<<(int)(((long long)NMESH * 64 + 255) / 256), 256, 0, stream>>>(
        Bb, deg, dinv, b2, off, esrc, ewt, A, NGRID, NMESH);

    // 5. mesh head: t1 = hm @ Wl + bl ; t2 = gelu(t1 @ Wl1 + bl1)
    gemm_k<1, 0><<<gMesh, 256, 0, stream>>>(A + (size_t)NGRID * HID, Wl, bl, Bb, NMESH, HID);
    gemm_k<1, 1><<<gMesh, 256, 0, stream>>>(Bb, Wl1, bl1, A, NMESH, HID);

    // 6. transpose to (256, NMESH)
    dim3 gT((NMESH + 31) / 32, HID / 32);
    transpose_k<<<gT, 256, 0, stream>>>(A, out);
}

// Round 3
// 495.090 us; speedup vs baseline: 8.2981x; 1.7390x over previous
//
#include <hip/hip_runtime.h>

#define NGRID 65160          // 181*360 grid nodes
#define NMESH 40962
#define NTOT  (NGRID + NMESH) // 106122
#define CIN   69
#define KPAD1 96             // CIN padded to multiple of 32
#define HID   256
#define HH    181
#define WWID  360
#define SCAN_BS 1024
#define NBLK_SCAN ((NTOT + SCAN_BS - 1) / SCAN_BS)   // 104

typedef short bs8 __attribute__((ext_vector_type(8)));
typedef float f32x4 __attribute__((ext_vector_type(4)));

__device__ __forceinline__ float gelu_exact(float v) {
    return 0.5f * v * (1.0f + erff(v * 0.7071067811865476f));
}
__device__ __forceinline__ ushort f2bf(float f) {   // RTNE
    unsigned u = __float_as_uint(f);
    return (ushort)((u + 0x7FFFu + ((u >> 16) & 1u)) >> 16);
}
__device__ __forceinline__ float bf2f(ushort h) {
    return __uint_as_float((unsigned)h << 16);
}

// ---------------- feature build: h0 (NTOT x 96 row-major, zero-padded) ------------
__global__ void build_feats(const float* __restrict__ x, const int* __restrict__ Lat,
                            const int* __restrict__ Lon, float* __restrict__ h0) {
    long long t = (long long)blockIdx.x * blockDim.x + threadIdx.x;
    if (t >= (long long)NTOT * KPAD1) return;
    int i = (int)(t / KPAD1);
    int c = (int)(t - (long long)i * KPAD1);
    float val = 0.f;
    if (c < CIN) {
        const float* xc = x + (size_t)c * (HH * WWID);
        if (i < NGRID) {
            val = xc[i];
        } else {
            int j = i - NGRID;
            int la = Lat[j] - 1;   // 0..720
            int lo = Lon[j] - 1;   // 0..1439
            if (la == 720) {
                val = xc[180 * WWID + 0];   // pole value x[c, -1, 0]
            } else {
                float sh = fmaxf((la + 0.5f) * 0.25f - 0.5f, 0.0f);
                int i0 = (int)floorf(sh); if (i0 > HH - 2) i0 = HH - 2;
                int i1 = i0 + 1; if (i1 > HH - 2) i1 = HH - 2;
                float wh = sh - (float)i0;
                float sw = fmaxf((lo + 0.5f) * 0.25f - 0.5f, 0.0f);
                int j0 = (int)floorf(sw); if (j0 > WWID - 1) j0 = WWID - 1;
                int j1 = j0 + 1; if (j1 > WWID - 1) j1 = WWID - 1;
                float ww = sw - (float)j0;
                float a = xc[i0 * WWID + j0] * (1.f - wh) + xc[i1 * WWID + j0] * wh;
                float b = xc[i0 * WWID + j1] * (1.f - wh) + xc[i1 * WWID + j1] * wh;
                val = a * (1.f - ww) + b * ww;
            }
        }
    }
    h0[(size_t)i * KPAD1 + c] = val;
}

// ---------------- degree / norm ----------------
__global__ void deg_init(float* __restrict__ deg, int* __restrict__ cnt) {
    int i = blockIdx.x * 256 + threadIdx.x;
    if (i < NTOT) { deg[i] = 1.0f; cnt[i] = 0; }
}
__global__ void deg_scatter(const int* __restrict__ ei, float* __restrict__ deg, int E) {
    int e = blockIdx.x * 256 + threadIdx.x;
    if (e < E) atomicAdd(&deg[ei[E + e]], 1.0f);
}
__global__ void dinv_k(const float* __restrict__ deg, float* __restrict__ dinv) {
    int i = blockIdx.x * 256 + threadIdx.x;
    if (i < NTOT) {
        float d = deg[i];
        dinv[i] = d > 0.f ? 1.0f / sqrtf(d) : 0.0f;
    }
}

// ---------------- exclusive scan of in-degree -> CSR offsets ----------------
__global__ __launch_bounds__(SCAN_BS) void scan1(const float* __restrict__ deg,
                                                 int* __restrict__ off, int* __restrict__ bsum) {
    __shared__ int s[SCAN_BS];
    int t = threadIdx.x;
    int i = blockIdx.x * SCAN_BS + t;
    int v = (i < NTOT) ? ((int)deg[i] - 1) : 0;
    s[t] = v; __syncthreads();
    for (int d = 1; d < SCAN_BS; d <<= 1) {
        int x = (t >= d) ? s[t - d] : 0;
        __syncthreads();
        s[t] += x;
        __syncthreads();
    }
    if (i < NTOT) off[i] = s[t] - v;          // exclusive
    if (t == SCAN_BS - 1) bsum[blockIdx.x] = s[t];
}
__global__ void scan2(int* __restrict__ bsum) {
    __shared__ int s[128];
    int t = threadIdx.x;
    int v = (t < NBLK_SCAN) ? bsum[t] : 0;
    s[t] = v; __syncthreads();
    for (int d = 1; d < 128; d <<= 1) {
        int x = (t >= d) ? s[t - d] : 0;
        __syncthreads();
        s[t] += x;
        __syncthreads();
    }
    if (t < NBLK_SCAN) bsum[t] = s[t] - v;    // exclusive block offsets
}
__global__ __launch_bounds__(SCAN_BS) void scan3(int* __restrict__ off, const int* __restrict__ bsum) {
    int i = blockIdx.x * SCAN_BS + threadIdx.x;
    if (i < NTOT) off[i] += bsum[blockIdx.x];
}

// ---------------- CSR fill ----------------
__global__ void csr_fill(const int* __restrict__ ei, const float* __restrict__ dinv,
                         const int* __restrict__ off, int* __restrict__ cnt,
                         int* __restrict__ esrc, float* __restrict__ ewt, int E) {
    int e = blockIdx.x * 256 + threadIdx.x;
    if (e >= E) return;
    int s = ei[e], d = ei[E + e];
    int pos = off[d] + atomicAdd(&cnt[d], 1);
    esrc[pos] = s;
    ewt[pos] = dinv[s] * dinv[d];
}

// ---------------- weight pack: W (Kw x 256) fp32 -> [Kpad/8][256][8] bf16 hi/lo -----
__global__ void pack_w(const float* __restrict__ W, ushort* __restrict__ hi,
                       ushort* __restrict__ lo, int Kw, int Kpad) {
    int t = blockIdx.x * 256 + threadIdx.x;
    if (t >= Kpad * HID) return;
    int k = t / HID, c = t % HID;
    float v = (k < Kw) ? W[(size_t)k * HID + c] : 0.f;
    ushort h = f2bf(v);
    ushort l = f2bf(v - bf2f(h));
    size_t idx = (((size_t)(k >> 3) * HID + c) << 3) + (k & 7);
    hi[idx] = h;
    lo[idx] = l;
}

// ---------------- MFMA GEMM: out(N x 256) = A(N x K) @ W(K x 256) --------
// split-bf16 (3 products). Block: 64 rows x 256 cols, 4 waves (64 cols each).
template<int KCHUNK, int BIAS, int GELU>
__global__ __launch_bounds__(256) void gemm_mfma(const float* __restrict__ A,
                                                 const ushort* __restrict__ WPhi,
                                                 const ushort* __restrict__ WPlo,
                                                 const float* __restrict__ bias,
                                                 float* __restrict__ out,
                                                 int Nrows, int K) {
    __shared__ ushort Ah[64 * KCHUNK];
    __shared__ ushort Al[64 * KCHUNK];
    const int row0 = blockIdx.x * 64;
    const int t = threadIdx.x;
    const int lane = t & 63;
    const int wave = t >> 6;
    const int l15 = lane & 15, l4 = lane >> 4;
    const int colw = wave * 64;

    f32x4 acc[4][4] = {};

    for (int kk = 0; kk < K; kk += KCHUNK) {
        __syncthreads();
        constexpr int F4PR = KCHUNK / 4;
        constexpr int ITER = (64 * F4PR) / 256;
#pragma unroll
        for (int i = 0; i < ITER; ++i) {
            int f = t + i * 256;
            int r = f / F4PR;
            int ks = (f % F4PR) * 4;
            int gr = row0 + r;
            float4 v = make_float4(0.f, 0.f, 0.f, 0.f);
            if (gr < Nrows) v = *(const float4*)(A + (size_t)gr * K + kk + ks);
            ushort h0v = f2bf(v.x), h1 = f2bf(v.y), h2 = f2bf(v.z), h3 = f2bf(v.w);
            ushort l0 = f2bf(v.x - bf2f(h0v)), l1 = f2bf(v.y - bf2f(h1));
            ushort l2 = f2bf(v.z - bf2f(h2)), l3 = f2bf(v.w - bf2f(h3));
            int byte = r * (KCHUNK * 2) + ks * 2;
            int swz = byte ^ ((r & 7) << 4);
            uint2 ph, pl;
            ph.x = (unsigned)h0v | ((unsigned)h1 << 16);
            ph.y = (unsigned)h2 | ((unsigned)h3 << 16);
            pl.x = (unsigned)l0 | ((unsigned)l1 << 16);
            pl.y = (unsigned)l2 | ((unsigned)l3 << 16);
            *(uint2*)((char*)Ah + swz) = ph;
            *(uint2*)((char*)Al + swz) = pl;
        }
        __syncthreads();
#pragma unroll
        for (int ks = 0; ks < KCHUNK; ks += 32) {
            bs8 ah[4], al[4];
#pragma unroll
            for (int rb = 0; rb < 4; ++rb) {
                int r = rb * 16 + l15;
                int k = ks + l4 * 8;
                int byte = r * (KCHUNK * 2) + k * 2;
                int swz = byte ^ ((r & 7) << 4);
                ah[rb] = *(bs8*)((char*)Ah + swz);
                al[rb] = *(bs8*)((char*)Al + swz);
            }
            bs8 bh[4], bl[4];
#pragma unroll
            for (int cb = 0; cb < 4; ++cb) {
                int c = colw + cb * 16 + l15;
                size_t g = (size_t)((kk + ks) >> 3) + l4;
                size_t off = (g * HID + c) << 3;
                bh[cb] = *(const bs8*)(WPhi + off);
                bl[cb] = *(const bs8*)(WPlo + off);
            }
#pragma unroll
            for (int rb = 0; rb < 4; ++rb)
#pragma unroll
                for (int cb = 0; cb < 4; ++cb) {
                    acc[rb][cb] = __builtin_amdgcn_mfma_f32_16x16x32_bf16(ah[rb], bh[cb], acc[rb][cb], 0, 0, 0);
                    acc[rb][cb] = __builtin_amdgcn_mfma_f32_16x16x32_bf16(ah[rb], bl[cb], acc[rb][cb], 0, 0, 0);
                    acc[rb][cb] = __builtin_amdgcn_mfma_f32_16x16x32_bf16(al[rb], bh[cb], acc[rb][cb], 0, 0, 0);
                }
        }
    }
#pragma unroll
    for (int rb = 0; rb < 4; ++rb) {
#pragma unroll
        for (int r = 0; r < 4; ++r) {
            int gr = row0 + rb * 16 + l4 * 4 + r;
            if (gr < Nrows) {
#pragma unroll
                for (int cb = 0; cb < 4; ++cb) {
                    int gc = colw + cb * 16 + l15;
                    float v = acc[rb][cb][r];
                    if (BIAS) v += bias[gc];
                    if (GELU) v = gelu_exact(v);
                    out[(size_t)gr * HID + gc] = v;
                }
            }
        }
    }
}

// ---------------- gather aggregation: one wave per dst ----------------
template<int GELU>
__global__ __launch_bounds__(256) void gather_agg(const float* __restrict__ tmp,
                                                  const float* __restrict__ deg,
                                                  const float* __restrict__ dinv,
                                                  const float* __restrict__ bias,
                                                  const int* __restrict__ off,
                                                  const int* __restrict__ esrc,
                                                  const float* __restrict__ ewt,
                                                  float* __restrict__ out,
                                                  int base, int ndst) {
    int wv = (blockIdx.x * 256 + threadIdx.x) >> 6;
    if (wv >= ndst) return;
    int d = base + wv;
    int lane = threadIdx.x & 63;
    float dv = dinv[d];
    float w2 = dv * dv;
    float4 acc = ((const float4*)bias)[lane];
    float4 v = ((const float4*)(tmp + (size_t)d * HID))[lane];
    acc.x = fmaf(w2, v.x, acc.x);
    acc.y = fmaf(w2, v.y, acc.y);
    acc.z = fmaf(w2, v.z, acc.z);
    acc.w = fmaf(w2, v.w, acc.w);
    int p0 = off[d];
    int p1 = p0 + ((int)deg[d] - 1);
    for (int p = p0; p < p1; ++p) {
        int s = esrc[p];
        float w = ewt[p];
        float4 u = ((const float4*)(tmp + (size_t)s * HID))[lane];
        acc.x = fmaf(w, u.x, acc.x);
        acc.y = fmaf(w, u.y, acc.y);
        acc.z = fmaf(w, u.z, acc.z);
        acc.w = fmaf(w, u.w, acc.w);
    }
    if (GELU) {
        acc.x = gelu_exact(acc.x);
        acc.y = gelu_exact(acc.y);
        acc.z = gelu_exact(acc.z);
        acc.w = gelu_exact(acc.w);
    }
    ((float4*)(out + (size_t)d * HID))[lane] = acc;
}

// ---------------- final transpose: (NMESH x 256) -> (256 x NMESH) ----------------
__global__ void transpose_k(const float* __restrict__ in, float* __restrict__ out) {
    __shared__ float tile[32][33];
    int jb = blockIdx.x * 32;
    int fb = blockIdx.y * 32;
    int tx = threadIdx.x & 31, ty = threadIdx.x >> 5;
#pragma unroll
    for (int i = 0; i < 32; i += 8) {
        int j = jb + ty + i;
        float v = 0.f;
        if (j < NMESH) v = in[(size_t)j * HID + fb + tx];
        tile[ty + i][tx] = v;
    }
    __syncthreads();
#pragma unroll
    for (int i = 0; i < 32; i += 8) {
        int f = fb + ty + i;
        int j = jb + tx;
        if (j < NMESH) out[(size_t)f * NMESH + j] = tile[tx][ty + i];
    }
}

extern "C" void kernel_launch(void* const* d_in, const int* in_sizes, int n_in,
                              void* d_out, int out_size, void* d_ws, size_t ws_size,
                              hipStream_t stream) {
    const float* x   = (const float*)d_in[0];
    const int*   ei  = (const int*)d_in[1];
    const int*   Lat = (const int*)d_in[2];
    const int*   Lon = (const int*)d_in[3];
    const float* W1  = (const float*)d_in[4];
    const float* b1  = (const float*)d_in[5];
    const float* W2  = (const float*)d_in[6];
    const float* b2  = (const float*)d_in[7];
    const float* Wl  = (const float*)d_in[8];
    const float* bl  = (const float*)d_in[9];
    const float* Wl1 = (const float*)d_in[10];
    const float* bl1 = (const float*)d_in[11];
    float* out = (float*)d_out;
    const int E = in_sizes[1] / 2;

    // d_out (256*NMESH = 10.49M floats = 41.9MB) doubles as scratch for h0 (40.75MB)
    // and later the CSR arrays; it is fully overwritten by the final transpose.
    float* h0   = (float*)d_out;                 // NTOT*96 fp32 (scratch until GEMM1)
    int*   esrc = (int*)d_out;                   // E ints   (after GEMM1)
    float* ewt  = (float*)d_out + E;             // E floats

    float* A    = (float*)d_ws;                  // NTOT*256
    float* Bb   = A    + (size_t)NTOT * HID;     // NTOT*256
    float* deg  = Bb   + (size_t)NTOT * HID;     // NTOT
    float* dinv = deg  + NTOT;                   // NTOT
    int*   off  = (int*)(dinv + NTOT);           // NTOT
    int*   cnt  = off + NTOT;                    // NTOT
    int*   bsum = cnt + NTOT;                    // 128
    ushort* wp  = (ushort*)(bsum + 128);
    ushort* W1h = wp;                            // 96*256
    ushort* W1l = W1h + KPAD1 * HID;
    ushort* W2h = W1l + KPAD1 * HID;             // 256*256 each below
    ushort* W2l = W2h + HID * HID;
    ushort* Wlh = W2l + HID * HID;
    ushort* Wll = Wlh + HID * HID;
    ushort* Wl1h= Wll + HID * HID;
    ushort* Wl1l= Wl1h + HID * HID;

    // 1. features (padded to K=96)
    {
        long long tot = (long long)NTOT * KPAD1;
        build_feats<<<(int)((tot + 255) / 256), 256, 0, stream>>>(x, Lat, Lon, h0);
    }
    // 2. degree / norm / CSR offsets / packed weights
    deg_init<<<(NTOT + 255) / 256, 256, 0, stream>>>(deg, cnt);
    deg_scatter<<<(E + 255) / 256, 256, 0, stream>>>(ei, deg, E);
    dinv_k<<<(NTOT + 255) / 256, 256, 0, stream>>>(deg, dinv);
    scan1<<<NBLK_SCAN, SCAN_BS, 0, stream>>>(deg, off, bsum);
    scan2<<<1, 128, 0, stream>>>(bsum);
    scan3<<<NBLK_SCAN, SCAN_BS, 0, stream>>>(off, bsum);
    pack_w<<<(KPAD1 * HID + 255) / 256, 256, 0, stream>>>(W1, W1h, W1l, CIN, KPAD1);
    pack_w<<<(HID * HID + 255) / 256, 256, 0, stream>>>(W2, W2h, W2l, HID, HID);
    pack_w<<<(HID * HID + 255) / 256, 256, 0, stream>>>(Wl, Wlh, Wll, HID, HID);
    pack_w<<<(HID * HID + 255) / 256, 256, 0, stream>>>(Wl1, Wl1h, Wl1l, HID, HID);

    const int gFull = (NTOT + 63) / 64;
    const int gMesh = (NMESH + 63) / 64;

    // 3. GCN layer 1: GEMM (h0 -> Bb), CSR fill (overwrites h0 region), gather+gelu
    gemm_mfma<KPAD1, 0, 0><<<gFull, 256, 0, stream>>>(h0, W1h, W1l, nullptr, Bb, NTOT, KPAD1);
    csr_fill<<<(E + 255) / 256, 256, 0, stream>>>(ei, dinv, off, cnt, esrc, ewt, E);
    gather_agg<1><<<(int)(((long long)NTOT * 64 + 255) / 256), 256, 0, stream>>>(
        Bb, deg, dinv, b1, off, esrc, ewt, A, 0, NTOT);

    // 4. GCN layer 2: GEMM full, gather only mesh dsts
    gemm_mfma<64, 0, 0><<<gFull, 256, 0, stream>>>(A, W2h, W2l, nullptr, Bb, NTOT, HID);
    gather_agg<0><<<(int)(((long long)NMESH * 64 + 255) / 256), 256, 0, stream>>>(
        Bb, deg, dinv, b2, off, esrc, ewt, A, NGRID, NMESH);

    // 5. mesh head
    gemm_mfma<64, 1, 0><<<gMesh, 256, 0, stream>>>(A + (size_t)NGRID * HID, Wlh, Wll, bl, Bb, NMESH, HID);
    gemm_mfma<64, 1, 1><<<gMesh, 256, 0, stream>>>(Bb, Wl1h, Wl1l, bl1, A, NMESH, HID);

    // 6. transpose to (256, NMESH) — overwrites the d_out scratch
    dim3 gT((NMESH + 31) / 32, HID / 32);
    transpose_k<<<gT, 256, 0, stream>>>(A, out);
}

// Round 4
// 415.824 us; speedup vs baseline: 9.8799x; 1.1906x over previous
//
#include <hip/hip_runtime.h>

#define NGRID 65160          // 181*360 grid nodes
#define NMESH 40962
#define NTOT  (NGRID + NMESH) // 106122
#define CIN   69
#define KPAD1 96             // CIN padded to multiple of 32
#define HID   256
#define HH    181
#define WWID  360
#define SCAN_BS 1024
#define NBLK_SCAN ((NTOT + SCAN_BS - 1) / SCAN_BS)   // 104

typedef short bs8 __attribute__((ext_vector_type(8)));
typedef float f32x4 __attribute__((ext_vector_type(4)));

__device__ __forceinline__ float gelu_exact(float v) {
    return 0.5f * v * (1.0f + erff(v * 0.7071067811865476f));
}
__device__ __forceinline__ ushort f2bf(float f) {   // RTNE
    unsigned u = __float_as_uint(f);
    return (ushort)((u + 0x7FFFu + ((u >> 16) & 1u)) >> 16);
}
__device__ __forceinline__ float bf2f(ushort h) {
    return __uint_as_float((unsigned)h << 16);
}

// ---------------- grid part of h0: transpose x[69][65160] -> h0[0:NGRID][96] -------
__global__ __launch_bounds__(256) void transpose_x(const float* __restrict__ x,
                                                   float* __restrict__ h0g) {
    __shared__ float tile[96][65];   // padded stride 65 -> conflict-light
    int s0 = blockIdx.x * 64;
    int t = threadIdx.x;
#pragma unroll
    for (int i = 0; i < 24; ++i) {   // 96 ch x 64 spatial / 256 thr
        int idx = t + i * 256;
        int c = idx >> 6, s = idx & 63;
        int gs = s0 + s;
        float v = 0.f;
        if (c < CIN && gs < NGRID) v = x[(size_t)c * NGRID + gs];
        tile[c][s] = v;
    }
    __syncthreads();
#pragma unroll
    for (int i = 0; i < 6; ++i) {    // 64 rows x 24 float4 / 256 thr
        int idx = t + i * 256;
        int r = idx / 24, c4 = idx % 24;
        int gr = s0 + r;
        if (gr < NGRID) {
            float4 v;
            v.x = tile[c4 * 4 + 0][r];
            v.y = tile[c4 * 4 + 1][r];
            v.z = tile[c4 * 4 + 2][r];
            v.w = tile[c4 * 4 + 3][r];
            ((float4*)h0g)[(size_t)gr * 24 + c4] = v;
        }
    }
}

// ---------------- mesh part of h0: bilinear4 gather from transposed grid ----------
__global__ __launch_bounds__(256) void mesh_interp(const float* __restrict__ h0g,
                                                   const int* __restrict__ Lat,
                                                   const int* __restrict__ Lon,
                                                   float* __restrict__ h0m) {
    int t = blockIdx.x * 256 + threadIdx.x;
    if (t >= NMESH * 24) return;
    int j = t / 24, c4 = t % 24;
    int la = Lat[j] - 1;   // 0..720
    int lo = Lon[j] - 1;   // 0..1439
    const float4* g = (const float4*)h0g;
    float4 v;
    if (la == 720) {
        v = g[(size_t)(180 * WWID) * 24 + c4];   // pole: x[c, -1, 0]
    } else {
        float sh = fmaxf((la + 0.5f) * 0.25f - 0.5f, 0.0f);
        int i0 = min((int)sh, HH - 2);           // 0..179 (sh >= 0)
        int i1 = min(i0 + 1, HH - 2);
        float wh = sh - (float)i0;
        float sw = fmaxf((lo + 0.5f) * 0.25f - 0.5f, 0.0f);
        int j0 = min((int)sw, WWID - 1);
        int j1 = min(j0 + 1, WWID - 1);
        float ww = sw - (float)j0;
        float4 v00 = g[(size_t)(i0 * WWID + j0) * 24 + c4];
        float4 v10 = g[(size_t)(i1 * WWID + j0) * 24 + c4];
        float4 v01 = g[(size_t)(i0 * WWID + j1) * 24 + c4];
        float4 v11 = g[(size_t)(i1 * WWID + j1) * 24 + c4];
        float4 a, b;
        a.x = v00.x + (v10.x - v00.x) * wh;  a.y = v00.y + (v10.y - v00.y) * wh;
        a.z = v00.z + (v10.z - v00.z) * wh;  a.w = v00.w + (v10.w - v00.w) * wh;
        b.x = v01.x + (v11.x - v01.x) * wh;  b.y = v01.y + (v11.y - v01.y) * wh;
        b.z = v01.z + (v11.z - v01.z) * wh;  b.w = v01.w + (v11.w - v01.w) * wh;
        v.x = a.x + (b.x - a.x) * ww;  v.y = a.y + (b.y - a.y) * ww;
        v.z = a.z + (b.z - a.z) * ww;  v.w = a.w + (b.w - a.w) * ww;
    }
    ((float4*)h0m)[(size_t)j * 24 + c4] = v;
}

// ---------------- degree / norm ----------------
__global__ void deg_init(float* __restrict__ deg, int* __restrict__ cnt) {
    int i = blockIdx.x * 256 + threadIdx.x;
    if (i < NTOT) { deg[i] = 1.0f; cnt[i] = 0; }
}
__global__ void deg_scatter(const int* __restrict__ ei, float* __restrict__ deg, int E) {
    int e = blockIdx.x * 256 + threadIdx.x;
    if (e < E) atomicAdd(&deg[ei[E + e]], 1.0f);
}
__global__ void dinv_k(const float* __restrict__ deg, float* __restrict__ dinv) {
    int i = blockIdx.x * 256 + threadIdx.x;
    if (i < NTOT) {
        float d = deg[i];
        dinv[i] = d > 0.f ? 1.0f / sqrtf(d) : 0.0f;
    }
}

// ---------------- exclusive scan of in-degree -> CSR offsets ----------------
__global__ __launch_bounds__(SCAN_BS) void scan1(const float* __restrict__ deg,
                                                 int* __restrict__ off, int* __restrict__ bsum) {
    __shared__ int s[SCAN_BS];
    int t = threadIdx.x;
    int i = blockIdx.x * SCAN_BS + t;
    int v = (i < NTOT) ? ((int)deg[i] - 1) : 0;
    s[t] = v; __syncthreads();
    for (int d = 1; d < SCAN_BS; d <<= 1) {
        int x = (t >= d) ? s[t - d] : 0;
        __syncthreads();
        s[t] += x;
        __syncthreads();
    }
    if (i < NTOT) off[i] = s[t] - v;          // exclusive
    if (t == SCAN_BS - 1) bsum[blockIdx.x] = s[t];
}
__global__ void scan2(int* __restrict__ bsum) {
    __shared__ int s[128];
    int t = threadIdx.x;
    int v = (t < NBLK_SCAN) ? bsum[t] : 0;
    s[t] = v; __syncthreads();
    for (int d = 1; d < 128; d <<= 1) {
        int x = (t >= d) ? s[t - d] : 0;
        __syncthreads();
        s[t] += x;
        __syncthreads();
    }
    if (t < NBLK_SCAN) bsum[t] = s[t] - v;    // exclusive block offsets
}
__global__ __launch_bounds__(SCAN_BS) void scan3(int* __restrict__ off, const int* __restrict__ bsum) {
    int i = blockIdx.x * SCAN_BS + threadIdx.x;
    if (i < NTOT) off[i] += bsum[blockIdx.x];
}

// ---------------- CSR fill ----------------
__global__ void csr_fill(const int* __restrict__ ei, const float* __restrict__ dinv,
                         const int* __restrict__ off, int* __restrict__ cnt,
                         int* __restrict__ esrc, float* __restrict__ ewt, int E) {
    int e = blockIdx.x * 256 + threadIdx.x;
    if (e >= E) return;
    int s = ei[e], d = ei[E + e];
    int pos = off[d] + atomicAdd(&cnt[d], 1);
    esrc[pos] = s;
    ewt[pos] = dinv[s] * dinv[d];
}

// ---------------- weight pack: W (Kw x 256) fp32 -> [Kpad/8][256][8] bf16 hi/lo -----
__global__ void pack_w(const float* __restrict__ W, ushort* __restrict__ hi,
                       ushort* __restrict__ lo, int Kw, int Kpad) {
    int t = blockIdx.x * 256 + threadIdx.x;
    if (t >= Kpad * HID) return;
    int k = t / HID, c = t % HID;
    float v = (k < Kw) ? W[(size_t)k * HID + c] : 0.f;
    ushort h = f2bf(v);
    ushort l = f2bf(v - bf2f(h));
    size_t idx = (((size_t)(k >> 3) * HID + c) << 3) + (k & 7);
    hi[idx] = h;
    lo[idx] = l;
}

// ---------------- MFMA GEMM: out(N x 256) = A(N x K) @ W(K x 256) --------
// split-bf16 (3 products). Block: 64 rows x 256 cols, 4 waves (64 cols each).
template<int KCHUNK, int BIAS, int GELU>
__global__ __launch_bounds__(256) void gemm_mfma(const float* __restrict__ A,
                                                 const ushort* __restrict__ WPhi,
                                                 const ushort* __restrict__ WPlo,
                                                 const float* __restrict__ bias,
                                                 float* __restrict__ out,
                                                 int Nrows, int K) {
    __shared__ ushort Ah[64 * KCHUNK];
    __shared__ ushort Al[64 * KCHUNK];
    const int row0 = blockIdx.x * 64;
    const int t = threadIdx.x;
    const int lane = t & 63;
    const int wave = t >> 6;
    const int l15 = lane & 15, l4 = lane >> 4;
    const int colw = wave * 64;

    f32x4 acc[4][4] = {};

    for (int kk = 0; kk < K; kk += KCHUNK) {
        __syncthreads();
        constexpr int F4PR = KCHUNK / 4;
        constexpr int ITER = (64 * F4PR) / 256;
#pragma unroll
        for (int i = 0; i < ITER; ++i) {
            int f = t + i * 256;
            int r = f / F4PR;
            int ks = (f % F4PR) * 4;
            int gr = row0 + r;
            float4 v = make_float4(0.f, 0.f, 0.f, 0.f);
            if (gr < Nrows) v = *(const float4*)(A + (size_t)gr * K + kk + ks);
            ushort h0v = f2bf(v.x), h1 = f2bf(v.y), h2 = f2bf(v.z), h3 = f2bf(v.w);
            ushort l0 = f2bf(v.x - bf2f(h0v)), l1 = f2bf(v.y - bf2f(h1));
            ushort l2 = f2bf(v.z - bf2f(h2)), l3 = f2bf(v.w - bf2f(h3));
            int byte = r * (KCHUNK * 2) + ks * 2;
            int swz = byte ^ ((r & 7) << 4);
            uint2 ph, pl;
            ph.x = (unsigned)h0v | ((unsigned)h1 << 16);
            ph.y = (unsigned)h2 | ((unsigned)h3 << 16);
            pl.x = (unsigned)l0 | ((unsigned)l1 << 16);
            pl.y = (unsigned)l2 | ((unsigned)l3 << 16);
            *(uint2*)((char*)Ah + swz) = ph;
            *(uint2*)((char*)Al + swz) = pl;
        }
        __syncthreads();
#pragma unroll
        for (int ks = 0; ks < KCHUNK; ks += 32) {
            bs8 ah[4], al[4];
#pragma unroll
            for (int rb = 0; rb < 4; ++rb) {
                int r = rb * 16 + l15;
                int k = ks + l4 * 8;
                int byte = r * (KCHUNK * 2) + k * 2;
                int swz = byte ^ ((r & 7) << 4);
                ah[rb] = *(bs8*)((char*)Ah + swz);
                al[rb] = *(bs8*)((char*)Al + swz);
            }
            bs8 bh[4], bl[4];
#pragma unroll
            for (int cb = 0; cb < 4; ++cb) {
                int c = colw + cb * 16 + l15;
                size_t g = (size_t)((kk + ks) >> 3) + l4;
                size_t off = (g * HID + c) << 3;
                bh[cb] = *(const bs8*)(WPhi + off);
                bl[cb] = *(const bs8*)(WPlo + off);
            }
#pragma unroll
            for (int rb = 0; rb < 4; ++rb)
#pragma unroll
                for (int cb = 0; cb < 4; ++cb) {
                    acc[rb][cb] = __builtin_amdgcn_mfma_f32_16x16x32_bf16(ah[rb], bh[cb], acc[rb][cb], 0, 0, 0);
                    acc[rb][cb] = __builtin_amdgcn_mfma_f32_16x16x32_bf16(ah[rb], bl[cb], acc[rb][cb], 0, 0, 0);
                    acc[rb][cb] = __builtin_amdgcn_mfma_f32_16x16x32_bf16(al[rb], bh[cb], acc[rb][cb], 0, 0, 0);
                }
        }
    }
#pragma unroll
    for (int rb = 0; rb < 4; ++rb) {
#pragma unroll
        for (int r = 0; r < 4; ++r) {
            int gr = row0 + rb * 16 + l4 * 4 + r;
            if (gr < Nrows) {
#pragma unroll
                for (int cb = 0; cb < 4; ++cb) {
                    int gc = colw + cb * 16 + l15;
                    float v = acc[rb][cb][r];
                    if (BIAS) v += bias[gc];
                    if (GELU) v = gelu_exact(v);
                    out[(size_t)gr * HID + gc] = v;
                }
            }
        }
    }
}

// ---------------- gather aggregation: one wave per dst ----------------
template<int GELU>
__global__ __launch_bounds__(256) void gather_agg(const float* __restrict__ tmp,
                                                  const float* __restrict__ deg,
                                                  const float* __restrict__ dinv,
                                                  const float* __restrict__ bias,
                                                  const int* __restrict__ off,
                                                  const int* __restrict__ esrc,
                                                  const float* __restrict__ ewt,
                                                  float* __restrict__ out,
                                                  int base, int ndst) {
    int wv = (blockIdx.x * 256 + threadIdx.x) >> 6;
    if (wv >= ndst) return;
    int d = base + wv;
    int lane = threadIdx.x & 63;
    float dv = dinv[d];
    float w2 = dv * dv;
    float4 acc = ((const float4*)bias)[lane];
    float4 v = ((const float4*)(tmp + (size_t)d * HID))[lane];
    acc.x = fmaf(w2, v.x, acc.x);
    acc.y = fmaf(w2, v.y, acc.y);
    acc.z = fmaf(w2, v.z, acc.z);
    acc.w = fmaf(w2, v.w, acc.w);
    int p0 = off[d];
    int p1 = p0 + ((int)deg[d] - 1);
    for (int p = p0; p < p1; ++p) {
        int s = esrc[p];
        float w = ewt[p];
        float4 u = ((const float4*)(tmp + (size_t)s * HID))[lane];
        acc.x = fmaf(w, u.x, acc.x);
        acc.y = fmaf(w, u.y, acc.y);
        acc.z = fmaf(w, u.z, acc.z);
        acc.w = fmaf(w, u.w, acc.w);
    }
    if (GELU) {
        acc.x = gelu_exact(acc.x);
        acc.y = gelu_exact(acc.y);
        acc.z = gelu_exact(acc.z);
        acc.w = gelu_exact(acc.w);
    }
    ((float4*)(out + (size_t)d * HID))[lane] = acc;
}

// ---------------- final transpose: (NMESH x 256) -> (256 x NMESH) ----------------
__global__ void transpose_k(const float* __restrict__ in, float* __restrict__ out) {
    __shared__ float tile[32][33];
    int jb = blockIdx.x * 32;
    int fb = blockIdx.y * 32;
    int tx = threadIdx.x & 31, ty = threadIdx.x >> 5;
#pragma unroll
    for (int i = 0; i < 32; i += 8) {
        int j = jb + ty + i;
        float v = 0.f;
        if (j < NMESH) v = in[(size_t)j * HID + fb + tx];
        tile[ty + i][tx] = v;
    }
    __syncthreads();
#pragma unroll
    for (int i = 0; i < 32; i += 8) {
        int f = fb + ty + i;
        int j = jb + tx;
        if (j < NMESH) out[(size_t)f * NMESH + j] = tile[tx][ty + i];
    }
}

extern "C" void kernel_launch(void* const* d_in, const int* in_sizes, int n_in,
                              void* d_out, int out_size, void* d_ws, size_t ws_size,
                              hipStream_t stream) {
    const float* x   = (const float*)d_in[0];
    const int*   ei  = (const int*)d_in[1];
    const int*   Lat = (const int*)d_in[2];
    const int*   Lon = (const int*)d_in[3];
    const float* W1  = (const float*)d_in[4];
    const float* b1  = (const float*)d_in[5];
    const float* W2  = (const float*)d_in[6];
    const float* b2  = (const float*)d_in[7];
    const float* Wl  = (const float*)d_in[8];
    const float* bl  = (const float*)d_in[9];
    const float* Wl1 = (const float*)d_in[10];
    const float* bl1 = (const float*)d_in[11];
    float* out = (float*)d_out;
    const int E = in_sizes[1] / 2;

    // d_out (256*NMESH = 41.9MB) doubles as scratch for h0 (NTOT*96*4 = 40.75MB)
    // and later the CSR arrays; fully overwritten by the final transpose.
    float* h0   = (float*)d_out;                 // NTOT*96 fp32 (scratch until GEMM1)
    int*   esrc = (int*)d_out;                   // E ints   (after GEMM1)
    float* ewt  = (float*)d_out + E;             // E floats

    float* A    = (float*)d_ws;                  // NTOT*256
    float* Bb   = A    + (size_t)NTOT * HID;     // NTOT*256
    float* deg  = Bb   + (size_t)NTOT * HID;     // NTOT
    float* dinv = deg  + NTOT;                   // NTOT
    int*   off  = (int*)(dinv + NTOT);           // NTOT
    int*   cnt  = off + NTOT;                    // NTOT
    int*   bsum = cnt + NTOT;                    // 128
    ushort* wp  = (ushort*)(bsum + 128);
    ushort* W1h = wp;                            // 96*256
    ushort* W1l = W1h + KPAD1 * HID;
    ushort* W2h = W1l + KPAD1 * HID;             // 256*256 each below
    ushort* W2l = W2h + HID * HID;
    ushort* Wlh = W2l + HID * HID;
    ushort* Wll = Wlh + HID * HID;
    ushort* Wl1h= Wll + HID * HID;
    ushort* Wl1l= Wl1h + HID * HID;

    // 1. features: coalesced transpose for grid rows, then L2-resident bilinear gather
    transpose_x<<<(NGRID + 63) / 64, 256, 0, stream>>>(x, h0);
    mesh_interp<<<(NMESH * 24 + 255) / 256, 256, 0, stream>>>(h0, Lat, Lon,
                                                              h0 + (size_t)NGRID * KPAD1);

    // 2. degree / norm / CSR offsets / packed weights
    deg_init<<<(NTOT + 255) / 256, 256, 0, stream>>>(deg, cnt);
    deg_scatter<<<(E + 255) / 256, 256, 0, stream>>>(ei, deg, E);
    dinv_k<<<(NTOT + 255) / 256, 256, 0, stream>>>(deg, dinv);
    scan1<<<NBLK_SCAN, SCAN_BS, 0, stream>>>(deg, off, bsum);
    scan2<<<1, 128, 0, stream>>>(bsum);
    scan3<<<NBLK_SCAN, SCAN_BS, 0, stream>>>(off, bsum);
    pack_w<<<(KPAD1 * HID + 255) / 256, 256, 0, stream>>>(W1, W1h, W1l, CIN, KPAD1);
    pack_w<<<(HID * HID + 255) / 256, 256, 0, stream>>>(W2, W2h, W2l, HID, HID);
    pack_w<<<(HID * HID + 255) / 256, 256, 0, stream>>>(Wl, Wlh, Wll, HID, HID);
    pack_w<<<(HID * HID + 255) / 256, 256, 0, stream>>>(Wl1, Wl1h, Wl1l, HID, HID);

    const int gFull = (NTOT + 63) / 64;
    const int gMesh = (NMESH + 63) / 64;

    // 3. GCN layer 1: GEMM (h0 -> Bb), CSR fill (overwrites h0 region), gather+gelu
    gemm_mfma<KPAD1, 0, 0><<<gFull, 256, 0, stream>>>(h0, W1h, W1l, nullptr, Bb, NTOT, KPAD1);
    csr_fill<<<(E + 255) / 256, 256, 0, stream>>>(ei, dinv, off, cnt, esrc, ewt, E);
    gather_agg<1><<<(int)(((long long)NTOT * 64 + 255) / 256), 256, 0, stream>>>(
        Bb, deg, dinv, b1, off, esrc, ewt, A, 0, NTOT);

    // 4. GCN layer 2: GEMM full, gather only mesh dsts
    gemm_mfma<64, 0, 0><<<gFull, 256, 0, stream>>>(A, W2h, W2l, nullptr, Bb, NTOT, HID);
    gather_agg<0><<<(int)(((long long)NMESH * 64 + 255) / 256), 256, 0, stream>>>(
        Bb, deg, dinv, b2, off, esrc, ewt, A, NGRID, NMESH);

    // 5. mesh head
    gemm_mfma<64, 1, 0><<<gMesh, 256, 0, stream>>>(A + (size_t)NGRID * HID, Wlh, Wll, bl, Bb, NMESH, HID);
    gemm_mfma<64, 1, 1><<<gMesh, 256, 0, stream>>>(Bb, Wl1h, Wl1l, bl1, A, NMESH, HID);

    // 6. transpose to (256, NMESH) — overwrites the d_out scratch
    dim3 gT((NMESH + 31) / 32, HID / 32);
    transpose_k<<<gT, 256, 0, stream>>>(A, out);
}

// Round 5
// 345.488 us; speedup vs baseline: 11.8913x; 1.2036x over previous
//
#include <hip/hip_runtime.h>

#define NGRID 65160          // 181*360 grid nodes
#define NMESH 40962
#define NTOT  (NGRID + NMESH) // 106122
#define CIN   69
#define KPAD1 96             // CIN padded to multiple of 32
#define HID   256
#define HH    181
#define WWID  360
#define SCAN_BS 1024
#define NBLK_SCAN ((NTOT + SCAN_BS - 1) / SCAN_BS)   // 104

typedef short bs8 __attribute__((ext_vector_type(8)));
typedef float f32x4 __attribute__((ext_vector_type(4)));
typedef _Float16 f16;
typedef _Float16 f16x2 __attribute__((ext_vector_type(2)));
typedef _Float16 f16x4 __attribute__((ext_vector_type(4)));

__device__ __forceinline__ float gelu_exact(float v) {
    return 0.5f * v * (1.0f + erff(v * 0.7071067811865476f));
}
__device__ __forceinline__ ushort f2bf(float f) {   // RTNE
    unsigned u = __float_as_uint(f);
    return (ushort)((u + 0x7FFFu + ((u >> 16) & 1u)) >> 16);
}
__device__ __forceinline__ float bf2f(ushort h) {
    return __uint_as_float((unsigned)h << 16);
}

// ---------------- grid part of h0: transpose x[69][65160] -> h0[0:NGRID][96] fp16 --
__global__ __launch_bounds__(256) void transpose_x(const float* __restrict__ x,
                                                   f16* __restrict__ h0g) {
    __shared__ float tile[96][65];
    int s0 = blockIdx.x * 64;
    int t = threadIdx.x;
#pragma unroll
    for (int i = 0; i < 24; ++i) {   // 96 ch x 64 spatial / 256 thr
        int idx = t + i * 256;
        int c = idx >> 6, s = idx & 63;
        int gs = s0 + s;
        float v = 0.f;
        if (c < CIN && gs < NGRID) v = x[(size_t)c * NGRID + gs];
        tile[c][s] = v;
    }
    __syncthreads();
#pragma unroll
    for (int i = 0; i < 12; ++i) {   // 64 rows x 48 f16x2 / 256 thr
        int idx = t + i * 256;
        int r = idx / 48, u = idx % 48;
        int gr = s0 + r;
        if (gr < NGRID) {
            f16x2 p;
            p.x = (f16)tile[u * 2 + 0][r];
            p.y = (f16)tile[u * 2 + 1][r];
            ((f16x2*)h0g)[(size_t)gr * 48 + u] = p;
        }
    }
}

// ---------------- mesh part of h0: bilinear4 gather from transposed grid ----------
__global__ __launch_bounds__(256) void mesh_interp(const f16* __restrict__ h0g,
                                                   const int* __restrict__ Lat,
                                                   const int* __restrict__ Lon,
                                                   f16* __restrict__ h0m) {
    int t = blockIdx.x * 256 + threadIdx.x;
    if (t >= NMESH * 48) return;
    int j = t / 48, u = t % 48;
    int la = Lat[j] - 1;   // 0..720
    int lo = Lon[j] - 1;   // 0..1439
    const f16x2* g = (const f16x2*)h0g;
    f16x2 o;
    if (la == 720) {
        o = g[(size_t)(180 * WWID) * 48 + u];   // pole: x[c, -1, 0]
    } else {
        float sh = fmaxf((la + 0.5f) * 0.25f - 0.5f, 0.0f);
        int i0 = min((int)sh, HH - 2);
        int i1 = min(i0 + 1, HH - 2);
        float wh = sh - (float)i0;
        float sw = fmaxf((lo + 0.5f) * 0.25f - 0.5f, 0.0f);
        int j0 = min((int)sw, WWID - 1);
        int j1 = min(j0 + 1, WWID - 1);
        float ww = sw - (float)j0;
        f16x2 v00 = g[(size_t)(i0 * WWID + j0) * 48 + u];
        f16x2 v10 = g[(size_t)(i1 * WWID + j0) * 48 + u];
        f16x2 v01 = g[(size_t)(i0 * WWID + j1) * 48 + u];
        f16x2 v11 = g[(size_t)(i1 * WWID + j1) * 48 + u];
        float ax = (float)v00.x + ((float)v10.x - (float)v00.x) * wh;
        float ay = (float)v00.y + ((float)v10.y - (float)v00.y) * wh;
        float bx = (float)v01.x + ((float)v11.x - (float)v01.x) * wh;
        float by = (float)v01.y + ((float)v11.y - (float)v01.y) * wh;
        o.x = (f16)(ax + (bx - ax) * ww);
        o.y = (f16)(ay + (by - ay) * ww);
    }
    ((f16x2*)h0m)[(size_t)j * 48 + u] = o;
}

// ---------------- degree / norm ----------------
__global__ void deg_init(float* __restrict__ deg, int* __restrict__ cnt) {
    int i = blockIdx.x * 256 + threadIdx.x;
    if (i < NTOT) { deg[i] = 1.0f; cnt[i] = 0; }
}
__global__ void deg_scatter(const int* __restrict__ ei, float* __restrict__ deg, int E) {
    int e = blockIdx.x * 256 + threadIdx.x;
    if (e < E) atomicAdd(&deg[ei[E + e]], 1.0f);
}
__global__ void dinv_k(const float* __restrict__ deg, float* __restrict__ dinv) {
    int i = blockIdx.x * 256 + threadIdx.x;
    if (i < NTOT) {
        float d = deg[i];
        dinv[i] = d > 0.f ? 1.0f / sqrtf(d) : 0.0f;
    }
}

// ---------------- exclusive scan of in-degree -> CSR offsets ----------------
__global__ __launch_bounds__(SCAN_BS) void scan1(const float* __restrict__ deg,
                                                 int* __restrict__ off, int* __restrict__ bsum) {
    __shared__ int s[SCAN_BS];
    int t = threadIdx.x;
    int i = blockIdx.x * SCAN_BS + t;
    int v = (i < NTOT) ? ((int)deg[i] - 1) : 0;
    s[t] = v; __syncthreads();
    for (int d = 1; d < SCAN_BS; d <<= 1) {
        int x = (t >= d) ? s[t - d] : 0;
        __syncthreads();
        s[t] += x;
        __syncthreads();
    }
    if (i < NTOT) off[i] = s[t] - v;          // exclusive
    if (t == SCAN_BS - 1) bsum[blockIdx.x] = s[t];
}
__global__ void scan2(int* __restrict__ bsum) {
    __shared__ int s[128];
    int t = threadIdx.x;
    int v = (t < NBLK_SCAN) ? bsum[t] : 0;
    s[t] = v; __syncthreads();
    for (int d = 1; d < 128; d <<= 1) {
        int x = (t >= d) ? s[t - d] : 0;
        __syncthreads();
        s[t] += x;
        __syncthreads();
    }
    if (t < NBLK_SCAN) bsum[t] = s[t] - v;    // exclusive block offsets
}
__global__ __launch_bounds__(SCAN_BS) void scan3(int* __restrict__ off, const int* __restrict__ bsum) {
    int i = blockIdx.x * SCAN_BS + threadIdx.x;
    if (i < NTOT) off[i] += bsum[blockIdx.x];
}

// ---------------- CSR fill ----------------
__global__ void csr_fill(const int* __restrict__ ei, const float* __restrict__ dinv,
                         const int* __restrict__ off, int* __restrict__ cnt,
                         int* __restrict__ esrc, float* __restrict__ ewt, int E) {
    int e = blockIdx.x * 256 + threadIdx.x;
    if (e >= E) return;
    int s = ei[e], d = ei[E + e];
    int pos = off[d] + atomicAdd(&cnt[d], 1);
    esrc[pos] = s;
    ewt[pos] = dinv[s] * dinv[d];
}

// ---------------- weight pack: W (Kw x 256) fp32 -> [Kpad/8][256][8] bf16 hi/lo -----
__global__ void pack_w(const float* __restrict__ W, ushort* __restrict__ hi,
                       ushort* __restrict__ lo, int Kw, int Kpad) {
    int t = blockIdx.x * 256 + threadIdx.x;
    if (t >= Kpad * HID) return;
    int k = t / HID, c = t % HID;
    float v = (k < Kw) ? W[(size_t)k * HID + c] : 0.f;
    ushort h = f2bf(v);
    ushort l = f2bf(v - bf2f(h));
    size_t idx = (((size_t)(k >> 3) * HID + c) << 3) + (k & 7);
    hi[idx] = h;
    lo[idx] = l;
}

// ---------------- agg1: out[d][96] f32 = dinv^2*h0[d] + sum w*h0[src]  (96-wide fp16 in)
__global__ __launch_bounds__(256) void agg1(const f16* __restrict__ h0,
                                            const float* __restrict__ deg,
                                            const float* __restrict__ dinv,
                                            const int* __restrict__ off,
                                            const int* __restrict__ esrc,
                                            const float* __restrict__ ewt,
                                            float* __restrict__ out) {
    int wv = (blockIdx.x * 256 + threadIdx.x) >> 6;
    if (wv >= NTOT) return;
    int lane = threadIdx.x & 63;
    if (lane >= 48) return;
    int d = wv;
    const f16x2* g = (const f16x2*)h0;
    float dv = dinv[d];
    float w2 = dv * dv;
    f16x2 v = g[(size_t)d * 48 + lane];
    float ax = w2 * (float)v.x;
    float ay = w2 * (float)v.y;
    int p0 = off[d];
    int p1 = p0 + ((int)deg[d] - 1);
    for (int p = p0; p < p1; ++p) {
        int s = esrc[p];
        float w = ewt[p];
        f16x2 u = g[(size_t)s * 48 + lane];
        ax = fmaf(w, (float)u.x, ax);
        ay = fmaf(w, (float)u.y, ay);
    }
    ((float2*)out)[(size_t)d * 48 + lane] = make_float2(ax, ay);
}

// ---------------- agg2: mesh dsts only; out[j][256] f32 from fp16 A rows ----------
__global__ __launch_bounds__(256) void agg2(const f16* __restrict__ A,
                                            const float* __restrict__ deg,
                                            const float* __restrict__ dinv,
                                            const int* __restrict__ off,
                                            const int* __restrict__ esrc,
                                            const float* __restrict__ ewt,
                                            float* __restrict__ out) {
    int wv = (blockIdx.x * 256 + threadIdx.x) >> 6;
    if (wv >= NMESH) return;
    int d = NGRID + wv;
    int lane = threadIdx.x & 63;
    const f16x4* g = (const f16x4*)A;
    float dv = dinv[d];
    float w2 = dv * dv;
    f16x4 v = g[(size_t)d * 64 + lane];
    float4 acc;
    acc.x = w2 * (float)v.x; acc.y = w2 * (float)v.y;
    acc.z = w2 * (float)v.z; acc.w = w2 * (float)v.w;
    int p0 = off[d];
    int p1 = p0 + ((int)deg[d] - 1);
    for (int p = p0; p < p1; ++p) {
        int s = esrc[p];
        float w = ewt[p];
        f16x4 u = g[(size_t)s * 64 + lane];
        acc.x = fmaf(w, (float)u.x, acc.x);
        acc.y = fmaf(w, (float)u.y, acc.y);
        acc.z = fmaf(w, (float)u.z, acc.z);
        acc.w = fmaf(w, (float)u.w, acc.w);
    }
    ((float4*)out)[(size_t)wv * 64 + lane] = acc;
}

// ---------------- MFMA GEMM: out(N x 256) = A(N x K) @ W(K x 256) --------
// split-bf16 (3 products). Block: 64 rows x 256 cols, 4 waves (64 cols each).
template<int KCHUNK, int BIAS, int GELU, int OUTHALF>
__global__ __launch_bounds__(256) void gemm_mfma(const float* __restrict__ A,
                                                 const ushort* __restrict__ WPhi,
                                                 const ushort* __restrict__ WPlo,
                                                 const float* __restrict__ bias,
                                                 void* __restrict__ out,
                                                 int Nrows, int K) {
    __shared__ ushort Ah[64 * KCHUNK];
    __shared__ ushort Al[64 * KCHUNK];
    const int row0 = blockIdx.x * 64;
    const int t = threadIdx.x;
    const int lane = t & 63;
    const int wave = t >> 6;
    const int l15 = lane & 15, l4 = lane >> 4;
    const int colw = wave * 64;

    f32x4 acc[4][4] = {};

    for (int kk = 0; kk < K; kk += KCHUNK) {
        __syncthreads();
        constexpr int F4PR = KCHUNK / 4;
        constexpr int ITER = (64 * F4PR) / 256;
#pragma unroll
        for (int i = 0; i < ITER; ++i) {
            int f = t + i * 256;
            int r = f / F4PR;
            int ks = (f % F4PR) * 4;
            int gr = row0 + r;
            float4 v = make_float4(0.f, 0.f, 0.f, 0.f);
            if (gr < Nrows) v = *(const float4*)(A + (size_t)gr * K + kk + ks);
            ushort h0v = f2bf(v.x), h1 = f2bf(v.y), h2 = f2bf(v.z), h3 = f2bf(v.w);
            ushort l0 = f2bf(v.x - bf2f(h0v)), l1 = f2bf(v.y - bf2f(h1));
            ushort l2 = f2bf(v.z - bf2f(h2)), l3 = f2bf(v.w - bf2f(h3));
            int byte = r * (KCHUNK * 2) + ks * 2;
            int swz = byte ^ ((r & 7) << 4);
            uint2 ph, pl;
            ph.x = (unsigned)h0v | ((unsigned)h1 << 16);
            ph.y = (unsigned)h2 | ((unsigned)h3 << 16);
            pl.x = (unsigned)l0 | ((unsigned)l1 << 16);
            pl.y = (unsigned)l2 | ((unsigned)l3 << 16);
            *(uint2*)((char*)Ah + swz) = ph;
            *(uint2*)((char*)Al + swz) = pl;
        }
        __syncthreads();
#pragma unroll
        for (int ks = 0; ks < KCHUNK; ks += 32) {
            bs8 ah[4], al[4];
#pragma unroll
            for (int rb = 0; rb < 4; ++rb) {
                int r = rb * 16 + l15;
                int k = ks + l4 * 8;
                int byte = r * (KCHUNK * 2) + k * 2;
                int swz = byte ^ ((r & 7) << 4);
                ah[rb] = *(bs8*)((char*)Ah + swz);
                al[rb] = *(bs8*)((char*)Al + swz);
            }
            bs8 bh[4], bl[4];
#pragma unroll
            for (int cb = 0; cb < 4; ++cb) {
                int c = colw + cb * 16 + l15;
                size_t g = (size_t)((kk + ks) >> 3) + l4;
                size_t off = (g * HID + c) << 3;
                bh[cb] = *(const bs8*)(WPhi + off);
                bl[cb] = *(const bs8*)(WPlo + off);
            }
#pragma unroll
            for (int rb = 0; rb < 4; ++rb)
#pragma unroll
                for (int cb = 0; cb < 4; ++cb) {
                    acc[rb][cb] = __builtin_amdgcn_mfma_f32_16x16x32_bf16(ah[rb], bh[cb], acc[rb][cb], 0, 0, 0);
                    acc[rb][cb] = __builtin_amdgcn_mfma_f32_16x16x32_bf16(ah[rb], bl[cb], acc[rb][cb], 0, 0, 0);
                    acc[rb][cb] = __builtin_amdgcn_mfma_f32_16x16x32_bf16(al[rb], bh[cb], acc[rb][cb], 0, 0, 0);
                }
        }
    }
#pragma unroll
    for (int rb = 0; rb < 4; ++rb) {
#pragma unroll
        for (int r = 0; r < 4; ++r) {
            int gr = row0 + rb * 16 + l4 * 4 + r;
            if (gr < Nrows) {
#pragma unroll
                for (int cb = 0; cb < 4; ++cb) {
                    int gc = colw + cb * 16 + l15;
                    float v = acc[rb][cb][r];
                    if (BIAS) v += bias[gc];
                    if (GELU) v = gelu_exact(v);
                    if (OUTHALF) ((f16*)out)[(size_t)gr * HID + gc] = (f16)v;
                    else         ((float*)out)[(size_t)gr * HID + gc] = v;
                }
            }
        }
    }
}

// ---------------- final transpose: (NMESH x 256) -> (256 x NMESH) ----------------
__global__ void transpose_k(const float* __restrict__ in, float* __restrict__ out) {
    __shared__ float tile[32][33];
    int jb = blockIdx.x * 32;
    int fb = blockIdx.y * 32;
    int tx = threadIdx.x & 31, ty = threadIdx.x >> 5;
#pragma unroll
    for (int i = 0; i < 32; i += 8) {
        int j = jb + ty + i;
        float v = 0.f;
        if (j < NMESH) v = in[(size_t)j * HID + fb + tx];
        tile[ty + i][tx] = v;
    }
    __syncthreads();
#pragma unroll
    for (int i = 0; i < 32; i += 8) {
        int f = fb + ty + i;
        int j = jb + tx;
        if (j < NMESH) out[(size_t)f * NMESH + j] = tile[tx][ty + i];
    }
}

extern "C" void kernel_launch(void* const* d_in, const int* in_sizes, int n_in,
                              void* d_out, int out_size, void* d_ws, size_t ws_size,
                              hipStream_t stream) {
    const float* x   = (const float*)d_in[0];
    const int*   ei  = (const int*)d_in[1];
    const int*   Lat = (const int*)d_in[2];
    const int*   Lon = (const int*)d_in[3];
    const float* W1  = (const float*)d_in[4];
    const float* b1  = (const float*)d_in[5];
    const float* W2  = (const float*)d_in[6];
    const float* b2  = (const float*)d_in[7];
    const float* Wl  = (const float*)d_in[8];
    const float* bl  = (const float*)d_in[9];
    const float* Wl1 = (const float*)d_in[10];
    const float* bl1 = (const float*)d_in[11];
    float* out = (float*)d_out;
    const int E = in_sizes[1] / 2;

    // d_out scratch timeline: [h0 fp16 (20.4MB) | esrc/ewt (4MB)] -> h2 f32 (41.9MB)
    // -> final transpose output. Each launch rewrites everything it reads.
    f16*   h0   = (f16*)d_out;                       // NTOT*96 fp16
    int*   esrc = (int*)((char*)d_out + (size_t)NTOT * KPAD1 * 2);
    float* ewt  = (float*)(esrc + E);
    float* h2   = (float*)d_out;                     // NMESH*256 f32 (after agg2)

    float* P0   = (float*)d_ws;                      // NTOT*96 f32 (agg1 out)
    f16*   Af   = (f16*)(P0 + (size_t)NTOT * KPAD1); // NTOT*256 f16 (gelu out)
    float* P2   = (float*)(Af + (size_t)NTOT * HID); // NMESH*256 f32
    float* P3   = P2 + (size_t)NMESH * HID;          // NMESH*256 f32
    float* deg  = P3 + (size_t)NMESH * HID;          // NTOT
    float* dinv = deg + NTOT;
    int*   off  = (int*)(dinv + NTOT);
    int*   cnt  = off + NTOT;
    int*   bsum = cnt + NTOT;                        // 128
    ushort* wp  = (ushort*)(bsum + 128);
    ushort* W1h = wp;
    ushort* W1l = W1h + KPAD1 * HID;
    ushort* W2h = W1l + KPAD1 * HID;
    ushort* W2l = W2h + HID * HID;
    ushort* Wlh = W2l + HID * HID;
    ushort* Wll = Wlh + HID * HID;
    ushort* Wl1h= Wll + HID * HID;
    ushort* Wl1l= Wl1h + HID * HID;

    // 1. features (fp16): coalesced transpose + L2-resident bilinear gather
    transpose_x<<<(NGRID + 63) / 64, 256, 0, stream>>>(x, h0);
    mesh_interp<<<(NMESH * 48 + 255) / 256, 256, 0, stream>>>(h0, Lat, Lon,
                                                              h0 + (size_t)NGRID * KPAD1);

    // 2. degree / norm / CSR / packed weights
    deg_init<<<(NTOT + 255) / 256, 256, 0, stream>>>(deg, cnt);
    deg_scatter<<<(E + 255) / 256, 256, 0, stream>>>(ei, deg, E);
    dinv_k<<<(NTOT + 255) / 256, 256, 0, stream>>>(deg, dinv);
    scan1<<<NBLK_SCAN, SCAN_BS, 0, stream>>>(deg, off, bsum);
    scan2<<<1, 128, 0, stream>>>(bsum);
    scan3<<<NBLK_SCAN, SCAN_BS, 0, stream>>>(off, bsum);
    csr_fill<<<(E + 255) / 256, 256, 0, stream>>>(ei, dinv, off, cnt, esrc, ewt, E);
    pack_w<<<(KPAD1 * HID + 255) / 256, 256, 0, stream>>>(W1, W1h, W1l, CIN, KPAD1);
    pack_w<<<(HID * HID + 255) / 256, 256, 0, stream>>>(W2, W2h, W2l, HID, HID);
    pack_w<<<(HID * HID + 255) / 256, 256, 0, stream>>>(Wl, Wlh, Wll, HID, HID);
    pack_w<<<(HID * HID + 255) / 256, 256, 0, stream>>>(Wl1, Wl1h, Wl1l, HID, HID);

    const int gFull = (NTOT + 63) / 64;
    const int gMesh = (NMESH + 63) / 64;

    // 3. layer 1: aggregate h0 (96-wide), then GEMM+bias+gelu -> A (fp16)
    agg1<<<(int)(((long long)NTOT * 64 + 255) / 256), 256, 0, stream>>>(
        h0, deg, dinv, off, esrc, ewt, P0);
    gemm_mfma<KPAD1, 1, 1, 1><<<gFull, 256, 0, stream>>>(P0, W1h, W1l, b1, Af, NTOT, KPAD1);

    // 4. layer 2: aggregate A for mesh dsts only, then GEMM+bias -> h2 (d_out)
    agg2<<<(int)(((long long)NMESH * 64 + 255) / 256), 256, 0, stream>>>(
        Af, deg, dinv, off, esrc, ewt, P2);
    gemm_mfma<64, 1, 0, 0><<<gMesh, 256, 0, stream>>>(P2, W2h, W2l, b2, h2, NMESH, HID);

    // 5. mesh head: t1 = h2 @ Wl + bl (-> P3); t2 = gelu(t1 @ Wl1 + bl1) (-> P2)
    gemm_mfma<64, 1, 0, 0><<<gMesh, 256, 0, stream>>>(h2, Wlh, Wll, bl, P3, NMESH, HID);
    gemm_mfma<64, 1, 1, 0><<<gMesh, 256, 0, stream>>>(P3, Wl1h, Wl1l, bl1, P2, NMESH, HID);

    // 6. transpose to (256, NMESH)
    dim3 gT((NMESH + 31) / 32, HID / 32);
    transpose_k<<<gT, 256, 0, stream>>>(P2, out);
}

// Round 6
// 313.869 us; speedup vs baseline: 13.0892x; 1.1007x over previous
//
#include <hip/hip_runtime.h>

#define NGRID 65160          // 181*360 grid nodes
#define NMESH 40962
#define NTOT  (NGRID + NMESH) // 106122
#define CIN   69
#define KPAD1 96             // CIN padded to multiple of 32
#define HID   256
#define HH    181
#define WWID  360
#define SCAN_BS 1024
#define NBLK_SCAN ((NTOT + SCAN_BS - 1) / SCAN_BS)   // 104

// packed-weight region offsets (ushort elements)
#define W1OFF  0
#define W2OFF  (96 * 256)
#define WLOFF  (W2OFF + 256 * 256)
#define WL1OFF (WLOFF + 256 * 256)
#define WALLK  (96 + 256 + 256 + 256)   // 864 total padded K rows

typedef short bs8 __attribute__((ext_vector_type(8)));
typedef float f32x4 __attribute__((ext_vector_type(4)));
typedef _Float16 f16;
typedef _Float16 f16x2 __attribute__((ext_vector_type(2)));
typedef _Float16 f16x4 __attribute__((ext_vector_type(4)));

__device__ __forceinline__ float gelu_exact(float v) {
    return 0.5f * v * (1.0f + erff(v * 0.7071067811865476f));
}
__device__ __forceinline__ ushort f2bf(float f) {   // RTNE
    unsigned u = __float_as_uint(f);
    return (ushort)((u + 0x7FFFu + ((u >> 16) & 1u)) >> 16);
}
__device__ __forceinline__ float bf2f(ushort h) {
    return __uint_as_float((unsigned)h << 16);
}

// ---------------- grid part of h0: transpose x[69][65160] -> h0[0:NGRID][96] fp16 --
__global__ __launch_bounds__(256) void transpose_x(const float* __restrict__ x,
                                                   f16* __restrict__ h0g) {
    __shared__ float tile[96][65];
    int s0 = blockIdx.x * 64;
    int t = threadIdx.x;
#pragma unroll
    for (int i = 0; i < 24; ++i) {
        int idx = t + i * 256;
        int c = idx >> 6, s = idx & 63;
        int gs = s0 + s;
        float v = 0.f;
        if (c < CIN && gs < NGRID) v = x[(size_t)c * NGRID + gs];
        tile[c][s] = v;
    }
    __syncthreads();
#pragma unroll
    for (int i = 0; i < 12; ++i) {
        int idx = t + i * 256;
        int r = idx / 48, u = idx % 48;
        int gr = s0 + r;
        if (gr < NGRID) {
            f16x2 p;
            p.x = (f16)tile[u * 2 + 0][r];
            p.y = (f16)tile[u * 2 + 1][r];
            ((f16x2*)h0g)[(size_t)gr * 48 + u] = p;
        }
    }
}

// ---------------- mesh part of h0: bilinear4 gather from transposed grid ----------
__global__ __launch_bounds__(256) void mesh_interp(const f16* __restrict__ h0g,
                                                   const int* __restrict__ Lat,
                                                   const int* __restrict__ Lon,
                                                   f16* __restrict__ h0m) {
    int t = blockIdx.x * 256 + threadIdx.x;
    if (t >= NMESH * 48) return;
    int j = t / 48, u = t % 48;
    int la = Lat[j] - 1;   // 0..720
    int lo = Lon[j] - 1;   // 0..1439
    const f16x2* g = (const f16x2*)h0g;
    f16x2 o;
    if (la == 720) {
        o = g[(size_t)(180 * WWID) * 48 + u];   // pole: x[c, -1, 0]
    } else {
        float sh = fmaxf((la + 0.5f) * 0.25f - 0.5f, 0.0f);
        int i0 = min((int)sh, HH - 2);
        int i1 = min(i0 + 1, HH - 2);
        float wh = sh - (float)i0;
        float sw = fmaxf((lo + 0.5f) * 0.25f - 0.5f, 0.0f);
        int j0 = min((int)sw, WWID - 1);
        int j1 = min(j0 + 1, WWID - 1);
        float ww = sw - (float)j0;
        f16x2 v00 = g[(size_t)(i0 * WWID + j0) * 48 + u];
        f16x2 v10 = g[(size_t)(i1 * WWID + j0) * 48 + u];
        f16x2 v01 = g[(size_t)(i0 * WWID + j1) * 48 + u];
        f16x2 v11 = g[(size_t)(i1 * WWID + j1) * 48 + u];
        float ax = (float)v00.x + ((float)v10.x - (float)v00.x) * wh;
        float ay = (float)v00.y + ((float)v10.y - (float)v00.y) * wh;
        float bx = (float)v01.x + ((float)v11.x - (float)v01.x) * wh;
        float by = (float)v01.y + ((float)v11.y - (float)v01.y) * wh;
        o.x = (f16)(ax + (bx - ax) * ww);
        o.y = (f16)(ay + (by - ay) * ww);
    }
    ((f16x2*)h0m)[(size_t)j * 48 + u] = o;
}

// ---------------- degree / norm ----------------
__global__ void deg_init(float* __restrict__ deg, int* __restrict__ cnt) {
    int i = blockIdx.x * 256 + threadIdx.x;
    if (i < NTOT) { deg[i] = 1.0f; cnt[i] = 0; }
}
__global__ void deg_scatter(const int* __restrict__ ei, float* __restrict__ deg, int E) {
    int e = blockIdx.x * 256 + threadIdx.x;
    if (e < E) atomicAdd(&deg[ei[E + e]], 1.0f);
}

// ---------------- exclusive scan of in-degree -> CSR offsets (+dinv) ----------------
__global__ __launch_bounds__(SCAN_BS) void scan1(const float* __restrict__ deg,
                                                 float* __restrict__ dinv,
                                                 int* __restrict__ off, int* __restrict__ bsum) {
    __shared__ int s[SCAN_BS];
    int t = threadIdx.x;
    int i = blockIdx.x * SCAN_BS + t;
    int v = (i < NTOT) ? ((int)deg[i] - 1) : 0;
    if (i < NTOT) dinv[i] = 1.0f / sqrtf((float)(v + 1));
    s[t] = v; __syncthreads();
    for (int d = 1; d < SCAN_BS; d <<= 1) {
        int x = (t >= d) ? s[t - d] : 0;
        __syncthreads();
        s[t] += x;
        __syncthreads();
    }
    if (i < NTOT) off[i] = s[t] - v;          // exclusive
    if (t == SCAN_BS - 1) bsum[blockIdx.x] = s[t];
}
__global__ void scan2(int* __restrict__ bsum) {
    __shared__ int s[128];
    int t = threadIdx.x;
    int v = (t < NBLK_SCAN) ? bsum[t] : 0;
    s[t] = v; __syncthreads();
    for (int d = 1; d < 128; d <<= 1) {
        int x = (t >= d) ? s[t - d] : 0;
        __syncthreads();
        s[t] += x;
        __syncthreads();
    }
    if (t < NBLK_SCAN) bsum[t] = s[t] - v;    // exclusive block offsets
}
__global__ __launch_bounds__(SCAN_BS) void scan3(int* __restrict__ off, const int* __restrict__ bsum) {
    int i = blockIdx.x * SCAN_BS + threadIdx.x;
    if (i < NTOT) off[i] += bsum[blockIdx.x];
}

// ---------------- CSR fill: packed (src, weight) ----------------
__global__ void csr_fill(const int* __restrict__ ei, const float* __restrict__ dinv,
                         const int* __restrict__ off, int* __restrict__ cnt,
                         int2* __restrict__ epk, int E) {
    int e = blockIdx.x * 256 + threadIdx.x;
    if (e >= E) return;
    int s = ei[e], d = ei[E + e];
    int pos = off[d] + atomicAdd(&cnt[d], 1);
    epk[pos] = make_int2(s, __float_as_int(dinv[s] * dinv[d]));
}

// ---------------- pack all weights -> [K/8][256][8] bf16 hi/lo regions ----------
__global__ void pack_all(const float* __restrict__ W1, const float* __restrict__ W2,
                         const float* __restrict__ Wl, const float* __restrict__ Wl1,
                         ushort* __restrict__ hi, ushort* __restrict__ lo) {
    int t = blockIdx.x * 256 + threadIdx.x;
    if (t >= WALLK * HID) return;
    int kg = t >> 8, c = t & 255;
    const float* src; int k, Kw; size_t base;
    if (kg < 96)       { src = W1;  k = kg;       Kw = CIN; base = W1OFF; }
    else if (kg < 352) { src = W2;  k = kg - 96;  Kw = HID; base = W2OFF; }
    else if (kg < 608) { src = Wl;  k = kg - 352; Kw = HID; base = WLOFF; }
    else               { src = Wl1; k = kg - 608; Kw = HID; base = WL1OFF; }
    float v = (k < Kw) ? src[(size_t)k * HID + c] : 0.f;
    ushort h = f2bf(v);
    ushort l = f2bf(v - bf2f(h));
    size_t idx = base + ((((size_t)(k >> 3)) * HID + c) << 3) + (k & 7);
    hi[idx] = h;
    lo[idx] = l;
}

// ---------------- agg1: out[d][96] f32 = dinv^2*h0[d] + sum w*h0[src]  (quad-unrolled)
__global__ __launch_bounds__(256) void agg1(const f16* __restrict__ h0,
                                            const float* __restrict__ deg,
                                            const float* __restrict__ dinv,
                                            const int* __restrict__ off,
                                            const int2* __restrict__ epk,
                                            float* __restrict__ out) {
    int wv = (blockIdx.x * 256 + threadIdx.x) >> 6;
    if (wv >= NTOT) return;
    int lane = threadIdx.x & 63;
    if (lane >= 48) return;
    int d = wv;
    const f16x2* g = (const f16x2*)h0;
    float dv = dinv[d];
    float w2 = dv * dv;
    f16x2 v = g[(size_t)d * 48 + lane];
    float ax = w2 * (float)v.x;
    float ay = w2 * (float)v.y;
    const int2* ep = epk + off[d];
    int n = (int)deg[d] - 1;
    int p = 0;
    for (; p + 4 <= n; p += 4) {
        int2 e0 = ep[p], e1 = ep[p + 1], e2 = ep[p + 2], e3 = ep[p + 3];
        f16x2 u0 = g[(size_t)e0.x * 48 + lane];
        f16x2 u1 = g[(size_t)e1.x * 48 + lane];
        f16x2 u2 = g[(size_t)e2.x * 48 + lane];
        f16x2 u3 = g[(size_t)e3.x * 48 + lane];
        float w0 = __int_as_float(e0.y), w1 = __int_as_float(e1.y);
        float w2b = __int_as_float(e2.y), w3 = __int_as_float(e3.y);
        ax = fmaf(w0, (float)u0.x, ax); ay = fmaf(w0, (float)u0.y, ay);
        ax = fmaf(w1, (float)u1.x, ax); ay = fmaf(w1, (float)u1.y, ay);
        ax = fmaf(w2b, (float)u2.x, ax); ay = fmaf(w2b, (float)u2.y, ay);
        ax = fmaf(w3, (float)u3.x, ax); ay = fmaf(w3, (float)u3.y, ay);
    }
    for (; p < n; ++p) {
        int2 e = ep[p];
        f16x2 u = g[(size_t)e.x * 48 + lane];
        float w = __int_as_float(e.y);
        ax = fmaf(w, (float)u.x, ax);
        ay = fmaf(w, (float)u.y, ay);
    }
    ((float2*)out)[(size_t)d * 48 + lane] = make_float2(ax, ay);
}

// ---------------- agg2: mesh dsts only; out[j][256] f32 from fp16 A rows ----------
__global__ __launch_bounds__(256) void agg2(const f16* __restrict__ A,
                                            const float* __restrict__ deg,
                                            const float* __restrict__ dinv,
                                            const int* __restrict__ off,
                                            const int2* __restrict__ epk,
                                            float* __restrict__ out) {
    int wv = (blockIdx.x * 256 + threadIdx.x) >> 6;
    if (wv >= NMESH) return;
    int d = NGRID + wv;
    int lane = threadIdx.x & 63;
    const f16x4* g = (const f16x4*)A;
    float dv = dinv[d];
    float w2 = dv * dv;
    f16x4 v = g[(size_t)d * 64 + lane];
    float4 acc;
    acc.x = w2 * (float)v.x; acc.y = w2 * (float)v.y;
    acc.z = w2 * (float)v.z; acc.w = w2 * (float)v.w;
    const int2* ep = epk + off[d];
    int n = (int)deg[d] - 1;
    int p = 0;
    for (; p + 4 <= n; p += 4) {
        int2 e0 = ep[p], e1 = ep[p + 1], e2 = ep[p + 2], e3 = ep[p + 3];
        f16x4 u0 = g[(size_t)e0.x * 64 + lane];
        f16x4 u1 = g[(size_t)e1.x * 64 + lane];
        f16x4 u2 = g[(size_t)e2.x * 64 + lane];
        f16x4 u3 = g[(size_t)e3.x * 64 + lane];
        float w0 = __int_as_float(e0.y), w1 = __int_as_float(e1.y);
        float w2b = __int_as_float(e2.y), w3 = __int_as_float(e3.y);
        acc.x = fmaf(w0, (float)u0.x, acc.x); acc.y = fmaf(w0, (float)u0.y, acc.y);
        acc.z = fmaf(w0, (float)u0.z, acc.z); acc.w = fmaf(w0, (float)u0.w, acc.w);
        acc.x = fmaf(w1, (float)u1.x, acc.x); acc.y = fmaf(w1, (float)u1.y, acc.y);
        acc.z = fmaf(w1, (float)u1.z, acc.z); acc.w = fmaf(w1, (float)u1.w, acc.w);
        acc.x = fmaf(w2b, (float)u2.x, acc.x); acc.y = fmaf(w2b, (float)u2.y, acc.y);
        acc.z = fmaf(w2b, (float)u2.z, acc.z); acc.w = fmaf(w2b, (float)u2.w, acc.w);
        acc.x = fmaf(w3, (float)u3.x, acc.x); acc.y = fmaf(w3, (float)u3.y, acc.y);
        acc.z = fmaf(w3, (float)u3.z, acc.z); acc.w = fmaf(w3, (float)u3.w, acc.w);
    }
    for (; p < n; ++p) {
        int2 e = ep[p];
        f16x4 u = g[(size_t)e.x * 64 + lane];
        float w = __int_as_float(e.y);
        acc.x = fmaf(w, (float)u.x, acc.x); acc.y = fmaf(w, (float)u.y, acc.y);
        acc.z = fmaf(w, (float)u.z, acc.z); acc.w = fmaf(w, (float)u.w, acc.w);
    }
    ((float4*)out)[(size_t)wv * 64 + lane] = acc;
}

// ---------------- MFMA GEMM (layer 1): out = A(N x 96) @ W1 + b1, gelu, fp16 out ---
template<int KCHUNK>
__global__ __launch_bounds__(256) void gemm_mfma(const float* __restrict__ A,
                                                 const ushort* __restrict__ WPhi,
                                                 const ushort* __restrict__ WPlo,
                                                 const float* __restrict__ bias,
                                                 f16* __restrict__ out,
                                                 int Nrows, int K) {
    __shared__ ushort Ah[64 * KCHUNK];
    __shared__ ushort Al[64 * KCHUNK];
    const int row0 = blockIdx.x * 64;
    const int t = threadIdx.x;
    const int lane = t & 63;
    const int wave = t >> 6;
    const int l15 = lane & 15, l4 = lane >> 4;
    const int colw = wave * 64;

    f32x4 acc[4][4] = {};

    for (int kk = 0; kk < K; kk += KCHUNK) {
        __syncthreads();
        constexpr int F4PR = KCHUNK / 4;
        constexpr int ITER = (64 * F4PR) / 256;
#pragma unroll
        for (int i = 0; i < ITER; ++i) {
            int f = t + i * 256;
            int r = f / F4PR;
            int ks = (f % F4PR) * 4;
            int gr = row0 + r;
            float4 v = make_float4(0.f, 0.f, 0.f, 0.f);
            if (gr < Nrows) v = *(const float4*)(A + (size_t)gr * K + kk + ks);
            ushort h0v = f2bf(v.x), h1 = f2bf(v.y), h2 = f2bf(v.z), h3 = f2bf(v.w);
            ushort l0 = f2bf(v.x - bf2f(h0v)), l1 = f2bf(v.y - bf2f(h1));
            ushort l2 = f2bf(v.z - bf2f(h2)), l3 = f2bf(v.w - bf2f(h3));
            int byte = r * (KCHUNK * 2) + ks * 2;
            int swz = byte ^ ((r & 7) << 4);
            uint2 ph, pl;
            ph.x = (unsigned)h0v | ((unsigned)h1 << 16);
            ph.y = (unsigned)h2 | ((unsigned)h3 << 16);
            pl.x = (unsigned)l0 | ((unsigned)l1 << 16);
            pl.y = (unsigned)l2 | ((unsigned)l3 << 16);
            *(uint2*)((char*)Ah + swz) = ph;
            *(uint2*)((char*)Al + swz) = pl;
        }
        __syncthreads();
#pragma unroll
        for (int ks = 0; ks < KCHUNK; ks += 32) {
            bs8 ah[4], al[4];
#pragma unroll
            for (int rb = 0; rb < 4; ++rb) {
                int r = rb * 16 + l15;
                int k = ks + l4 * 8;
                int byte = r * (KCHUNK * 2) + k * 2;
                int swz = byte ^ ((r & 7) << 4);
                ah[rb] = *(bs8*)((char*)Ah + swz);
                al[rb] = *(bs8*)((char*)Al + swz);
            }
            bs8 bh[4], bl[4];
#pragma unroll
            for (int cb = 0; cb < 4; ++cb) {
                int c = colw + cb * 16 + l15;
                size_t g = (size_t)((kk + ks) >> 3) + l4;
                size_t off = (g * HID + c) << 3;
                bh[cb] = *(const bs8*)(WPhi + off);
                bl[cb] = *(const bs8*)(WPlo + off);
            }
#pragma unroll
            for (int rb = 0; rb < 4; ++rb)
#pragma unroll
                for (int cb = 0; cb < 4; ++cb) {
                    acc[rb][cb] = __builtin_amdgcn_mfma_f32_16x16x32_bf16(ah[rb], bh[cb], acc[rb][cb], 0, 0, 0);
                    acc[rb][cb] = __builtin_amdgcn_mfma_f32_16x16x32_bf16(ah[rb], bl[cb], acc[rb][cb], 0, 0, 0);
                    acc[rb][cb] = __builtin_amdgcn_mfma_f32_16x16x32_bf16(al[rb], bh[cb], acc[rb][cb], 0, 0, 0);
                }
        }
    }
#pragma unroll
    for (int rb = 0; rb < 4; ++rb) {
#pragma unroll
        for (int r = 0; r < 4; ++r) {
            int gr = row0 + rb * 16 + l4 * 4 + r;
            if (gr < Nrows) {
#pragma unroll
                for (int cb = 0; cb < 4; ++cb) {
                    int gc = colw + cb * 16 + l15;
                    float v = acc[rb][cb][r] + bias[gc];
                    out[(size_t)gr * HID + gc] = (f16)gelu_exact(v);
                }
            }
        }
    }
}

// ---------------- fused mesh head: 3 chained GEMMs + gelu + transposed output -----
// out(256 x NMESH) = T( gelu( ((P2@W2+b2)@Wl+bl)@Wl1 + bl1 ) )
__global__ __launch_bounds__(256) void mesh_head(const float* __restrict__ P2,
                                                 const ushort* __restrict__ Whi,
                                                 const ushort* __restrict__ Wlo,
                                                 const float* __restrict__ b2,
                                                 const float* __restrict__ bl,
                                                 const float* __restrict__ bl1,
                                                 float* __restrict__ out) {
    __shared__ char smem[64 * 256 * 2 * 2];       // Ah (32KB) | Al (32KB)
    ushort* Ah = (ushort*)smem;
    ushort* Al = (ushort*)(smem + 32768);
    float* tb = (float*)smem;                     // [64][65] alias, transpose stage
    const int row0 = blockIdx.x * 64;
    const int t = threadIdx.x;
    const int lane = t & 63;
    const int wave = t >> 6;
    const int l15 = lane & 15, l4 = lane >> 4;
    const int colw = wave * 64;

    // stage P2 rows full-width (f32 -> bf16 hi/lo, swizzled)
#pragma unroll
    for (int i = 0; i < 16; ++i) {
        int idx = t + i * 256;          // 0..4095
        int r = idx >> 6;
        int ks = (idx & 63) * 4;
        int gr = row0 + r;
        float4 v = make_float4(0.f, 0.f, 0.f, 0.f);
        if (gr < NMESH) v = *(const float4*)(P2 + (size_t)gr * HID + ks);
        ushort h0v = f2bf(v.x), h1 = f2bf(v.y), h2 = f2bf(v.z), h3 = f2bf(v.w);
        ushort l0 = f2bf(v.x - bf2f(h0v)), l1 = f2bf(v.y - bf2f(h1));
        ushort l2 = f2bf(v.z - bf2f(h2)), l3 = f2bf(v.w - bf2f(h3));
        int byte = r * 512 + ks * 2;
        int swz = byte ^ ((r & 7) << 4);
        uint2 ph, pl;
        ph.x = (unsigned)h0v | ((unsigned)h1 << 16);
        ph.y = (unsigned)h2 | ((unsigned)h3 << 16);
        pl.x = (unsigned)l0 | ((unsigned)l1 << 16);
        pl.y = (unsigned)l2 | ((unsigned)l3 << 16);
        *(uint2*)((char*)Ah + swz) = ph;
        *(uint2*)((char*)Al + swz) = pl;
    }
    __syncthreads();

    f32x4 acc[4][4];

    auto run_pass = [&](const ushort* bhp, const ushort* blp, const float* bias) {
#pragma unroll
        for (int rb = 0; rb < 4; ++rb)
#pragma unroll
            for (int cb = 0; cb < 4; ++cb) acc[rb][cb] = (f32x4)0.f;
#pragma unroll
        for (int ks = 0; ks < HID; ks += 32) {
            bs8 ah[4], al[4];
#pragma unroll
            for (int rb = 0; rb < 4; ++rb) {
                int r = rb * 16 + l15;
                int k = ks + l4 * 8;
                int byte = r * 512 + k * 2;
                int swz = byte ^ ((r & 7) << 4);
                ah[rb] = *(bs8*)((char*)Ah + swz);
                al[rb] = *(bs8*)((char*)Al + swz);
            }
            bs8 bh[4], bl_[4];
#pragma unroll
            for (int cb = 0; cb < 4; ++cb) {
                int c = colw + cb * 16 + l15;
                size_t g = (size_t)(ks >> 3) + l4;
                size_t off = (g * HID + c) << 3;
                bh[cb] = *(const bs8*)(bhp + off);
                bl_[cb] = *(const bs8*)(blp + off);
            }
#pragma unroll
            for (int rb = 0; rb < 4; ++rb)
#pragma unroll
                for (int cb = 0; cb < 4; ++cb) {
                    acc[rb][cb] = __builtin_amdgcn_mfma_f32_16x16x32_bf16(ah[rb], bh[cb], acc[rb][cb], 0, 0, 0);
                    acc[rb][cb] = __builtin_amdgcn_mfma_f32_16x16x32_bf16(ah[rb], bl_[cb], acc[rb][cb], 0, 0, 0);
                    acc[rb][cb] = __builtin_amdgcn_mfma_f32_16x16x32_bf16(al[rb], bh[cb], acc[rb][cb], 0, 0, 0);
                }
        }
        // bias
#pragma unroll
        for (int cb = 0; cb < 4; ++cb) {
            float bv = bias[colw + cb * 16 + l15];
#pragma unroll
            for (int rb = 0; rb < 4; ++rb)
#pragma unroll
                for (int r = 0; r < 4; ++r) acc[rb][cb][r] += bv;
        }
    };

    auto restage = [&]() {
        __syncthreads();   // everyone done reading Ah/Al
#pragma unroll
        for (int rb = 0; rb < 4; ++rb)
#pragma unroll
            for (int cb = 0; cb < 4; ++cb)
#pragma unroll
                for (int r = 0; r < 4; ++r) {
                    int row = rb * 16 + l4 * 4 + r;
                    int col = colw + cb * 16 + l15;
                    float v = acc[rb][cb][r];
                    ushort h = f2bf(v);
                    ushort l = f2bf(v - bf2f(h));
                    int byte = row * 512 + col * 2;
                    int swz = byte ^ ((row & 7) << 4);
                    *(ushort*)((char*)Ah + swz) = h;
                    *(ushort*)((char*)Al + swz) = l;
                }
        __syncthreads();
    };

    run_pass(Whi + W2OFF, Wlo + W2OFF, b2);
    restage();
    run_pass(Whi + WLOFF, Wlo + WLOFF, bl);
    restage();
    run_pass(Whi + WL1OFF, Wlo + WL1OFF, bl1);
    // gelu
#pragma unroll
    for (int rb = 0; rb < 4; ++rb)
#pragma unroll
        for (int cb = 0; cb < 4; ++cb)
#pragma unroll
            for (int r = 0; r < 4; ++r) acc[rb][cb][r] = gelu_exact(acc[rb][cb][r]);

    // transposed write, one 64-col chunk (= one wave's acc) at a time
    for (int q = 0; q < 4; ++q) {
        __syncthreads();   // tb aliases Ah: safe, all passes done
        if (wave == q) {
#pragma unroll
            for (int rb = 0; rb < 4; ++rb)
#pragma unroll
                for (int cb = 0; cb < 4; ++cb)
#pragma unroll
                    for (int r = 0; r < 4; ++r) {
                        int row = rb * 16 + l4 * 4 + r;
                        int col = cb * 16 + l15;
                        tb[row * 65 + col] = acc[rb][cb][r];
                    }
        }
        __syncthreads();
        if (row0 + 64 <= NMESH) {
#pragma unroll
            for (int i = 0; i < 4; ++i) {
                int idx = t + i * 256;           // 0..1023
                int cl = idx >> 4, rq = idx & 15;
                float4 v;
                v.x = tb[(rq * 4 + 0) * 65 + cl];
                v.y = tb[(rq * 4 + 1) * 65 + cl];
                v.z = tb[(rq * 4 + 2) * 65 + cl];
                v.w = tb[(rq * 4 + 3) * 65 + cl];
                *(float4*)(out + (size_t)(q * 64 + cl) * NMESH + row0 + rq * 4) = v;
            }
        } else {
#pragma unroll
            for (int i = 0; i < 4; ++i) {
                int idx = t + i * 256;
                int cl = idx >> 4, rq = idx & 15;
#pragma unroll
                for (int j = 0; j < 4; ++j) {
                    int r = rq * 4 + j;
                    if (row0 + r < NMESH)
                        out[(size_t)(q * 64 + cl) * NMESH + row0 + r] = tb[r * 65 + cl];
                }
            }
        }
    }
}

extern "C" void kernel_launch(void* const* d_in, const int* in_sizes, int n_in,
                              void* d_out, int out_size, void* d_ws, size_t ws_size,
                              hipStream_t stream) {
    const float* x   = (const float*)d_in[0];
    const int*   ei  = (const int*)d_in[1];
    const int*   Lat = (const int*)d_in[2];
    const int*   Lon = (const int*)d_in[3];
    const float* W1  = (const float*)d_in[4];
    const float* b1  = (const float*)d_in[5];
    const float* W2  = (const float*)d_in[6];
    const float* b2  = (const float*)d_in[7];
    const float* Wl  = (const float*)d_in[8];
    const float* bl  = (const float*)d_in[9];
    const float* Wl1 = (const float*)d_in[10];
    const float* bl1 = (const float*)d_in[11];
    float* out = (float*)d_out;
    const int E = in_sizes[1] / 2;

    // d_out scratch: h0 fp16 (20.4MB) + epk (4MB); final mesh_head write overwrites all.
    f16*   h0  = (f16*)d_out;                        // NTOT*96 fp16
    int2*  epk = (int2*)((char*)d_out + (size_t)NTOT * KPAD1 * 2);

    float* P0   = (float*)d_ws;                      // NTOT*96 f32 (agg1 out)
    f16*   Af   = (f16*)(P0 + (size_t)NTOT * KPAD1); // NTOT*256 f16 (gelu out)
    float* P2   = (float*)(Af + (size_t)NTOT * HID); // NMESH*256 f32
    float* deg  = P2 + (size_t)NMESH * HID;          // NTOT
    float* dinv = deg + NTOT;
    int*   off  = (int*)(dinv + NTOT);
    int*   cnt  = off + NTOT;
    int*   bsum = cnt + NTOT;                        // 128
    ushort* hiW = (ushort*)(bsum + 128);             // WALLK*256
    ushort* loW = hiW + (size_t)WALLK * HID;

    // 1. features (fp16)
    transpose_x<<<(NGRID + 63) / 64, 256, 0, stream>>>(x, h0);
    mesh_interp<<<(NMESH * 48 + 255) / 256, 256, 0, stream>>>(h0, Lat, Lon,
                                                              h0 + (size_t)NGRID * KPAD1);

    // 2. degree / norm / CSR / packed weights
    deg_init<<<(NTOT + 255) / 256, 256, 0, stream>>>(deg, cnt);
    deg_scatter<<<(E + 255) / 256, 256, 0, stream>>>(ei, deg, E);
    scan1<<<NBLK_SCAN, SCAN_BS, 0, stream>>>(deg, dinv, off, bsum);
    scan2<<<1, 128, 0, stream>>>(bsum);
    scan3<<<NBLK_SCAN, SCAN_BS, 0, stream>>>(off, bsum);
    csr_fill<<<(E + 255) / 256, 256, 0, stream>>>(ei, dinv, off, cnt, epk, E);
    pack_all<<<(WALLK * HID + 255) / 256, 256, 0, stream>>>(W1, W2, Wl, Wl1, hiW, loW);

    // 3. layer 1: aggregate h0 (96-wide), GEMM+bias+gelu -> Af (fp16)
    agg1<<<(int)(((long long)NTOT * 64 + 255) / 256), 256, 0, stream>>>(
        h0, deg, dinv, off, epk, P0);
    gemm_mfma<KPAD1><<<(NTOT + 63) / 64, 256, 0, stream>>>(
        P0, hiW + W1OFF, loW + W1OFF, b1, Af, NTOT, KPAD1);

    // 4. layer 2 aggregation (mesh dsts only)
    agg2<<<(int)(((long long)NMESH * 64 + 255) / 256), 256, 0, stream>>>(
        Af, deg, dinv, off, epk, P2);

    // 5. fused mesh head: 3 GEMMs + gelu + transposed store
    mesh_head<<<(NMESH + 63) / 64, 256, 0, stream>>>(P2, hiW, loW, b2, bl, bl1, out);
}